// Round 9
// baseline (139.765 us; speedup 1.0000x reference)
//
#include <hip/hip_runtime.h>
#include <hip/hip_bf16.h>
#include <math.h>

#define BB 256
#define FF 1024
#define GG 512
#define SS 512
#define EE 256
#define PP 8
#define TT 256

typedef __attribute__((ext_vector_type(8))) short bs8;     // 8 bf16
typedef __attribute__((ext_vector_type(4))) float f32x4;

__device__ __forceinline__ float sigmoidf_(float x) { return 1.0f / (1.0f + expf(-x)); }

__device__ __forceinline__ short f2bf(float f) {
    union { float f; unsigned u; } v; v.f = f;
    unsigned r = v.u + 0x7FFFu + ((v.u >> 16) & 1u);   // RNE
    return (short)(r >> 16);
}

union BPack { bs8 s; __hip_bfloat162 h[4]; };

__device__ __forceinline__ bs8 ld8cvt(const float* p) {
    float4 a = *(const float4*)p, b = *(const float4*)(p + 4);
    BPack u;
    u.h[0] = __float22bfloat162_rn({a.x, a.y});
    u.h[1] = __float22bfloat162_rn({a.z, a.w});
    u.h[2] = __float22bfloat162_rn({b.x, b.y});
    u.h[3] = __float22bfloat162_rn({b.z, b.w});
    return u.s;
}
__device__ __forceinline__ void ld8split(const float* p, bs8& ho, bs8& lo) {
    float4 a = *(const float4*)p, b = *(const float4*)(p + 4);
    float v[8] = {a.x, a.y, a.z, a.w, b.x, b.y, b.z, b.w};
    BPack uh, ul;
#pragma unroll
    for (int j = 0; j < 4; ++j) {
        __hip_bfloat162 h2 = __float22bfloat162_rn({v[2*j], v[2*j+1]});
        uh.h[j] = h2;
        float r0 = v[2*j]   - __low2float(h2);
        float r1 = v[2*j+1] - __high2float(h2);
        ul.h[j] = __float22bfloat162_rn({r0, r1});
    }
    ho = uh.s; lo = ul.s;
}

// ---------------------------------------------------------------------------
// W slab layout (elements)
// ---------------------------------------------------------------------------
#define OWG_IH 0L
#define OWG_HH 2359296L
#define OWP_IH 3145728L
#define OWP_HH 5505024L
#define OWE_IH 6291456L
#define OWE_HH 6684672L
#define WTOT   6881280L

// k_mega block ranges
#define MC1 3360     // W slab conv
#define MC2 3488     // feature -> xg[:, :F]
#define MC3 3552     // h_g -> hg_bf
#define MC4 3584     // emotion0 -> emo_bf
#define MC5 3840     // gather
#define MCE 3872     // x_ split GEMM (32 blocks)

__global__ __launch_bounds__(256) void k_mega(
        const float* __restrict__ Wg_ih, const float* __restrict__ Wg_hh,
        const float* __restrict__ Wp_ih, const float* __restrict__ Wp_hh,
        const float* __restrict__ We_ih, const float* __restrict__ We_hh,
        const float* __restrict__ attn_W, const float* __restrict__ feature_,
        const float* __restrict__ h_g, const float* __restrict__ emotion0,
        const float* __restrict__ mask, const float* __restrict__ sp0,
        short* __restrict__ Wbf, short* __restrict__ xg,
        short* __restrict__ hg_bf, short* __restrict__ emo_bf, short* __restrict__ sel0_bf,
        float* __restrict__ sel0, int* __restrict__ spk, float* __restrict__ x_) {
    __shared__ __align__(16) char smem[32768];
    int blk = blockIdx.x, tid = threadIdx.x;
    if (blk < MC1) {
        long i = (long)blk * 2048 + tid * 8;
        const float* src; long base;
        if      (i < OWG_HH) { src = Wg_ih; base = OWG_IH; }
        else if (i < OWP_IH) { src = Wg_hh; base = OWG_HH; }
        else if (i < OWP_HH) { src = Wp_ih; base = OWP_IH; }
        else if (i < OWE_IH) { src = Wp_hh; base = OWP_HH; }
        else if (i < OWE_HH) { src = We_ih; base = OWE_IH; }
        else                 { src = We_hh; base = OWE_HH; }
        *(bs8*)(Wbf + i) = ld8cvt(src + (i - base));
    } else if (blk < MC2) {
        long i = (long)(blk - MC1) * 2048 + tid * 8;
        long b = i >> 10, c = i & 1023;
        *(bs8*)(xg + b * 1536 + c) = ld8cvt(feature_ + i);
    } else if (blk < MC3) {
        long i = (long)(blk - MC2) * 2048 + tid * 8;
        *(bs8*)(hg_bf + i) = ld8cvt(h_g + i);
    } else if (blk < MC4) {
        long i = (long)(blk - MC3) * 2048 + tid * 8;
        *(bs8*)(emo_bf + i) = ld8cvt(emotion0 + i);
    } else if (blk < MC5) {
        int b = blk - MC4;
        int* sid = (int*)smem;
        if (tid == 0) {
            int best = 0; float bv = mask[b * PP];
            for (int p = 1; p < PP; ++p) { float v = mask[b * PP + p]; if (v > bv) { bv = v; best = p; } }
            *sid = best; spk[b] = best;
        }
        __syncthreads();
        const float* src = sp0 + ((size_t)b * PP + *sid) * SS;
        for (int j = tid; j < SS; j += 256) {
            float v = src[j];
            sel0[(size_t)b * SS + j] = v;
            short h = f2bf(v);
            sel0_bf[(size_t)b * SS + j] = h;
            xg[(size_t)b * 1536 + FF + j] = h;
        }
    } else {
        // x_ = feature @ attn_W^T, split hi/lo, fp32-staged (no mega dependency)
        short* Ash = (short*)smem;
        short* Asl = (short*)(smem + 8192);
        short* Bsh = (short*)(smem + 16384);
        short* Bsl = (short*)(smem + 24576);
        int local = blk - MC5;
        int bm = local >> 3, bn = local & 7;
        const int lane = tid & 63, wid = tid >> 6;
        const int wr = wid >> 1, wc = wid & 1;
        const int r0 = tid >> 3, c0 = tid & 7;
        const int r1 = r0 + 32;
        const int la = lane & 15, lk = lane >> 4;
        const int sw = la & 7;

        f32x4 acc[2][2] = {};
        for (int k0 = 0; k0 < FF; k0 += 64) {
            bs8 ah0, ah1, bh0, bh1, al0, al1, bl0, bl1;
            ld8split(feature_ + (size_t)(bm * 64 + r0) * FF + k0 + c0 * 8, ah0, al0);
            ld8split(feature_ + (size_t)(bm * 64 + r1) * FF + k0 + c0 * 8, ah1, al1);
            ld8split(attn_W   + (size_t)(bn * 64 + r0) * FF + k0 + c0 * 8, bh0, bl0);
            ld8split(attn_W   + (size_t)(bn * 64 + r1) * FF + k0 + c0 * 8, bh1, bl1);
            __syncthreads();
            *(bs8*)(Ash + r0 * 64 + ((c0 ^ (r0 & 7)) * 8)) = ah0;
            *(bs8*)(Ash + r1 * 64 + ((c0 ^ (r1 & 7)) * 8)) = ah1;
            *(bs8*)(Asl + r0 * 64 + ((c0 ^ (r0 & 7)) * 8)) = al0;
            *(bs8*)(Asl + r1 * 64 + ((c0 ^ (r1 & 7)) * 8)) = al1;
            *(bs8*)(Bsh + r0 * 64 + ((c0 ^ (r0 & 7)) * 8)) = bh0;
            *(bs8*)(Bsh + r1 * 64 + ((c0 ^ (r1 & 7)) * 8)) = bh1;
            *(bs8*)(Bsl + r0 * 64 + ((c0 ^ (r0 & 7)) * 8)) = bl0;
            *(bs8*)(Bsl + r1 * 64 + ((c0 ^ (r1 & 7)) * 8)) = bl1;
            __syncthreads();
#pragma unroll
            for (int kk = 0; kk < 2; ++kk) {
                int slot = kk * 4 + lk;
                int off = (slot ^ sw) * 8;
                bs8 a0 = *(const bs8*)(Ash + (wr * 32 + la) * 64      + off);
                bs8 a1 = *(const bs8*)(Ash + (wr * 32 + 16 + la) * 64 + off);
                bs8 x0 = *(const bs8*)(Asl + (wr * 32 + la) * 64      + off);
                bs8 x1 = *(const bs8*)(Asl + (wr * 32 + 16 + la) * 64 + off);
                bs8 b0 = *(const bs8*)(Bsh + (wc * 32 + la) * 64      + off);
                bs8 b1 = *(const bs8*)(Bsh + (wc * 32 + 16 + la) * 64 + off);
                bs8 y0 = *(const bs8*)(Bsl + (wc * 32 + la) * 64      + off);
                bs8 y1 = *(const bs8*)(Bsl + (wc * 32 + 16 + la) * 64 + off);
                acc[0][0] = __builtin_amdgcn_mfma_f32_16x16x32_bf16(a0, b0, acc[0][0], 0, 0, 0);
                acc[0][0] = __builtin_amdgcn_mfma_f32_16x16x32_bf16(a0, y0, acc[0][0], 0, 0, 0);
                acc[0][0] = __builtin_amdgcn_mfma_f32_16x16x32_bf16(x0, b0, acc[0][0], 0, 0, 0);
                acc[0][1] = __builtin_amdgcn_mfma_f32_16x16x32_bf16(a0, b1, acc[0][1], 0, 0, 0);
                acc[0][1] = __builtin_amdgcn_mfma_f32_16x16x32_bf16(a0, y1, acc[0][1], 0, 0, 0);
                acc[0][1] = __builtin_amdgcn_mfma_f32_16x16x32_bf16(x0, b1, acc[0][1], 0, 0, 0);
                acc[1][0] = __builtin_amdgcn_mfma_f32_16x16x32_bf16(a1, b0, acc[1][0], 0, 0, 0);
                acc[1][0] = __builtin_amdgcn_mfma_f32_16x16x32_bf16(a1, y0, acc[1][0], 0, 0, 0);
                acc[1][0] = __builtin_amdgcn_mfma_f32_16x16x32_bf16(x1, b0, acc[1][0], 0, 0, 0);
                acc[1][1] = __builtin_amdgcn_mfma_f32_16x16x32_bf16(a1, b1, acc[1][1], 0, 0, 0);
                acc[1][1] = __builtin_amdgcn_mfma_f32_16x16x32_bf16(a1, y1, acc[1][1], 0, 0, 0);
                acc[1][1] = __builtin_amdgcn_mfma_f32_16x16x32_bf16(x1, b1, acc[1][1], 0, 0, 0);
            }
        }
        const int rowb = (lane >> 4) * 4, coln = lane & 15;
#pragma unroll
        for (int i = 0; i < 2; ++i)
#pragma unroll
        for (int j = 0; j < 2; ++j)
#pragma unroll
        for (int r = 0; r < 4; ++r) {
            int row = bm * 64 + wr * 32 + i * 16 + rowb + r;
            int col = bn * 64 + wc * 32 + j * 16 + coln;
            x_[(size_t)row * GG + col] = acc[i][j][r];
        }
    }
}

// ---------------------------------------------------------------------------
// k_main: blocks [0, NGEMM) = batched bf16 GEMM (non-split);
//         blocks [NGEMM, NGEMM+2048) = flash-attention partials.
// ---------------------------------------------------------------------------
struct GDesc {
    const short *A, *A2, *W;
    float* C;
    int lda, lda2, kb, ldw, woff, ldc, K, nbn;
};
struct GBatch {
    GDesc d[5];
    int start[6];
    int ng;
};

__global__ __launch_bounds__(256) void k_main(GBatch gb,
                                              const float* __restrict__ x_,
                                              const float* __restrict__ gh,
                                              float* __restrict__ ctxp,
                                              float2* __restrict__ msb) {
    __shared__ __align__(16) char smem[16448];
    int bid = blockIdx.x, tid = threadIdx.x;
    int ngemm = gb.start[gb.ng];

    if (bid < ngemm) {
        short* Ash = (short*)smem;
        short* Bsh = (short*)(smem + 8192);
        int g = 0;
        while (g + 1 < gb.ng && bid >= gb.start[g + 1]) ++g;
        GDesc d = gb.d[g];
        int local = bid - gb.start[g];
        int bn = local % d.nbn, bm = local / d.nbn;

        const int lane = tid & 63, wid = tid >> 6;
        const int wr = wid >> 1, wc = wid & 1;
        const int r0 = tid >> 3, c0 = tid & 7;
        const int r1 = r0 + 32;
        const int la = lane & 15, lk = lane >> 4;
        const int sw = la & 7;

        f32x4 acc[2][2] = {};
        for (int k0 = 0; k0 < d.K; k0 += 64) {
            const short* Ab; int alda;
            if (k0 < d.kb) { Ab = d.A + k0; alda = d.lda; }
            else           { Ab = d.A2 + (k0 - d.kb); alda = d.lda2; }
            bs8 ah0 = *(const bs8*)(Ab + (size_t)(bm * 64 + r0) * alda + c0 * 8);
            bs8 ah1 = *(const bs8*)(Ab + (size_t)(bm * 64 + r1) * alda + c0 * 8);
            bs8 bh0 = *(const bs8*)(d.W + (size_t)(bn * 64 + r0) * d.ldw + d.woff + k0 + c0 * 8);
            bs8 bh1 = *(const bs8*)(d.W + (size_t)(bn * 64 + r1) * d.ldw + d.woff + k0 + c0 * 8);
            __syncthreads();
            *(bs8*)(Ash + r0 * 64 + ((c0 ^ (r0 & 7)) * 8)) = ah0;
            *(bs8*)(Ash + r1 * 64 + ((c0 ^ (r1 & 7)) * 8)) = ah1;
            *(bs8*)(Bsh + r0 * 64 + ((c0 ^ (r0 & 7)) * 8)) = bh0;
            *(bs8*)(Bsh + r1 * 64 + ((c0 ^ (r1 & 7)) * 8)) = bh1;
            __syncthreads();
#pragma unroll
            for (int kk = 0; kk < 2; ++kk) {
                int slot = kk * 4 + lk;
                int off = (slot ^ sw) * 8;
                bs8 a0 = *(const bs8*)(Ash + (wr * 32 + la) * 64      + off);
                bs8 a1 = *(const bs8*)(Ash + (wr * 32 + 16 + la) * 64 + off);
                bs8 b0 = *(const bs8*)(Bsh + (wc * 32 + la) * 64      + off);
                bs8 b1 = *(const bs8*)(Bsh + (wc * 32 + 16 + la) * 64 + off);
                acc[0][0] = __builtin_amdgcn_mfma_f32_16x16x32_bf16(a0, b0, acc[0][0], 0, 0, 0);
                acc[0][1] = __builtin_amdgcn_mfma_f32_16x16x32_bf16(a0, b1, acc[0][1], 0, 0, 0);
                acc[1][0] = __builtin_amdgcn_mfma_f32_16x16x32_bf16(a1, b0, acc[1][0], 0, 0, 0);
                acc[1][1] = __builtin_amdgcn_mfma_f32_16x16x32_bf16(a1, b1, acc[1][1], 0, 0, 0);
            }
        }
        const int rowb = (lane >> 4) * 4, coln = lane & 15;
#pragma unroll
        for (int i = 0; i < 2; ++i)
#pragma unroll
        for (int j = 0; j < 2; ++j)
#pragma unroll
        for (int r = 0; r < 4; ++r) {
            int row = bm * 64 + wr * 32 + i * 16 + rowb + r;
            int col = bn * 64 + wc * 32 + j * 16 + coln;
            d.C[(size_t)row * d.ldc + col] = acc[i][j][r];
        }
        return;
    }

    // ---- flash attention partials
    int blk = bid - ngemm;                       // 0..2047
    int b = blk & (BB - 1), ch = blk >> 8;
    int w = tid >> 6, lane = tid & 63;
    float (*part)[GG] = (float(*)[GG])smem;      // 4 x 512 floats
    float* wm = (float*)(smem + 8192);           // 4
    float* ws = wm + 4;                          // 4

    const float* xb = x_ + (size_t)b * GG + lane * 8;
    float4 xa = *(const float4*)xb;
    float4 xc = *(const float4*)(xb + 4);

    float m = -INFINITY, s = 0.f;
    float acc[8] = {};
    int t0 = ch * 32 + w * 8;
#pragma unroll
    for (int it = 0; it < 8; ++it) {
        int t = t0 + it;
        const float* row = gh + ((size_t)t * BB + b) * GG + lane * 8;
        float4 v1 = *(const float4*)row;
        float4 v2 = *(const float4*)(row + 4);
        float p = v1.x*xa.x + v1.y*xa.y + v1.z*xa.z + v1.w*xa.w
                + v2.x*xc.x + v2.y*xc.y + v2.z*xc.z + v2.w*xc.w;
#pragma unroll
        for (int off = 32; off; off >>= 1) p += __shfl_xor(p, off);
        float nm = fmaxf(m, p);
        float scale = expf(m - nm);
        float e = expf(p - nm);
        s = s * scale + e;
        acc[0] = acc[0]*scale + e*v1.x; acc[1] = acc[1]*scale + e*v1.y;
        acc[2] = acc[2]*scale + e*v1.z; acc[3] = acc[3]*scale + e*v1.w;
        acc[4] = acc[4]*scale + e*v2.x; acc[5] = acc[5]*scale + e*v2.y;
        acc[6] = acc[6]*scale + e*v2.z; acc[7] = acc[7]*scale + e*v2.w;
        m = nm;
    }
    if (lane == 0) { wm[w] = m; ws[w] = s; }
    *(float4*)&part[w][lane * 8]     = make_float4(acc[0], acc[1], acc[2], acc[3]);
    *(float4*)&part[w][lane * 8 + 4] = make_float4(acc[4], acc[5], acc[6], acc[7]);
    __syncthreads();

    float M = fmaxf(fmaxf(wm[0], wm[1]), fmaxf(wm[2], wm[3]));
    float f0 = expf(wm[0] - M), f1 = expf(wm[1] - M);
    float f2 = expf(wm[2] - M), f3 = expf(wm[3] - M);
    if (tid == 0) {
        float S = ws[0]*f0 + ws[1]*f1 + ws[2]*f2 + ws[3]*f3;
        msb[blk] = make_float2(M, S);
    }
    for (int j = tid; j < GG; j += 256) {
        float r = part[0][j]*f0 + part[1][j]*f1 + part[2][j]*f2 + part[3][j]*f3;
        ctxp[(size_t)blk * GG + j] = r;
    }
}

// ---------------------------------------------------------------------------
// k_tailA: blocks [0,32): per-K-step flash-merge + ctx@Wp_ih[:,F:] 3-gate
//          GEMM + parties-GRU epilogue (par_bf + speaker scatter).
//          blocks [32,544): global GRU elementwise (fill).
// LDS: 8KB A + 24KB B + 2KB factors = 34KB (4 blocks/CU for fill).
// ---------------------------------------------------------------------------
#define T1G 32
__global__ __launch_bounds__(256) void k_tailA(
        const float* __restrict__ ctxp, const float2* __restrict__ msb,
        const short* __restrict__ Wp_ih_bf,
        const float* __restrict__ gi_p, const float* __restrict__ gh_p,
        const float* __restrict__ bp_ih, const float* __restrict__ bp_hh,
        const float* __restrict__ sel0, const int* __restrict__ spk,
        short* __restrict__ par_bf, float* __restrict__ speaker_out,
        const float* __restrict__ gi_g, const float* __restrict__ gh_g,
        const float* __restrict__ bg_ih, const float* __restrict__ bg_hh,
        const float* __restrict__ hg, float* __restrict__ global_out) {
    __shared__ __align__(16) char smem[34816];
    int bid = blockIdx.x, tid = threadIdx.x;
    if (bid >= T1G) {
        int idx = (bid - T1G) * 256 + tid;          // over B*G
        int b = idx / GG, j = idx - b * GG;
        const float* gib = gi_g + (size_t)b * 3 * GG;
        const float* ghb = gh_g + (size_t)b * 3 * GG;
        float r = sigmoidf_(gib[j] + bg_ih[j] + ghb[j] + bg_hh[j]);
        float z = sigmoidf_(gib[GG + j] + bg_ih[GG + j] + ghb[GG + j] + bg_hh[GG + j]);
        float n = tanhf(gib[2*GG + j] + bg_ih[2*GG + j] + r * (ghb[2*GG + j] + bg_hh[2*GG + j]));
        global_out[idx] = (1.0f - z) * n + z * hg[idx];
        return;
    }

    short* Ash = (short*)smem;                       // 8KB
    float* fl  = (float*)(smem + 32768);             // 64 x 8 factors

    int bm = bid >> 3, bn = bid & 7;
    int brow = bm * 64;

    if (tid < 64) {
        int b = brow + tid;
        float mv[8], sv[8];
        float M = -INFINITY;
#pragma unroll
        for (int c = 0; c < 8; ++c) {
            float2 t = msb[c * BB + b];
            mv[c] = t.x; sv[c] = t.y;
            M = fmaxf(M, t.x);
        }
        float fv[8], S = 0.f;
#pragma unroll
        for (int c = 0; c < 8; ++c) { fv[c] = expf(mv[c] - M); S += sv[c] * fv[c]; }
        float inv = 1.0f / S;
#pragma unroll
        for (int c = 0; c < 8; ++c) fl[tid * 8 + c] = fv[c] * inv;
    }
    __syncthreads();

    const int lane = tid & 63, wid = tid >> 6;
    const int wr = wid >> 1, wc = wid & 1;
    const int r0 = tid >> 3, c0 = tid & 7;
    const int r1 = r0 + 32;
    const int la = lane & 15, lk = lane >> 4;
    const int sw = la & 7;

    f32x4 acc[3][2][2] = {};

    for (int k0 = 0; k0 < 512; k0 += 64) {
        // merged-ctx A granules for rows r0, r1 (fp32 merge -> bf16, same order as R7)
        float a0v[8] = {}, a1v[8] = {};
#pragma unroll
        for (int c = 0; c < 8; ++c) {
            float fc0 = fl[r0 * 8 + c], fc1 = fl[r1 * 8 + c];
            const float* p0 = ctxp + ((size_t)(c * BB + brow + r0)) * GG + k0 + c0 * 8;
            const float* p1 = ctxp + ((size_t)(c * BB + brow + r1)) * GG + k0 + c0 * 8;
            float4 u1 = *(const float4*)p0, u2 = *(const float4*)(p0 + 4);
            float4 w1 = *(const float4*)p1, w2 = *(const float4*)(p1 + 4);
            a0v[0] += fc0*u1.x; a0v[1] += fc0*u1.y; a0v[2] += fc0*u1.z; a0v[3] += fc0*u1.w;
            a0v[4] += fc0*u2.x; a0v[5] += fc0*u2.y; a0v[6] += fc0*u2.z; a0v[7] += fc0*u2.w;
            a1v[0] += fc1*w1.x; a1v[1] += fc1*w1.y; a1v[2] += fc1*w1.z; a1v[3] += fc1*w1.w;
            a1v[4] += fc1*w2.x; a1v[5] += fc1*w2.y; a1v[6] += fc1*w2.z; a1v[7] += fc1*w2.w;
        }
        BPack u0, u1p;
        u0.h[0] = __float22bfloat162_rn({a0v[0], a0v[1]});
        u0.h[1] = __float22bfloat162_rn({a0v[2], a0v[3]});
        u0.h[2] = __float22bfloat162_rn({a0v[4], a0v[5]});
        u0.h[3] = __float22bfloat162_rn({a0v[6], a0v[7]});
        u1p.h[0] = __float22bfloat162_rn({a1v[0], a1v[1]});
        u1p.h[1] = __float22bfloat162_rn({a1v[2], a1v[3]});
        u1p.h[2] = __float22bfloat162_rn({a1v[4], a1v[5]});
        u1p.h[3] = __float22bfloat162_rn({a1v[6], a1v[7]});

        bs8 b0g[3], b1g[3];
#pragma unroll
        for (int g = 0; g < 3; ++g) {
            b0g[g] = *(const bs8*)(Wp_ih_bf + (size_t)(g * 512 + bn * 64 + r0) * 1536 + FF + k0 + c0 * 8);
            b1g[g] = *(const bs8*)(Wp_ih_bf + (size_t)(g * 512 + bn * 64 + r1) * 1536 + FF + k0 + c0 * 8);
        }
        __syncthreads();
        *(bs8*)(Ash + r0 * 64 + ((c0 ^ (r0 & 7)) * 8)) = u0.s;
        *(bs8*)(Ash + r1 * 64 + ((c0 ^ (r1 & 7)) * 8)) = u1p.s;
#pragma unroll
        for (int g = 0; g < 3; ++g) {
            short* Bg = (short*)(smem + 8192 + g * 8192);
            *(bs8*)(Bg + r0 * 64 + ((c0 ^ (r0 & 7)) * 8)) = b0g[g];
            *(bs8*)(Bg + r1 * 64 + ((c0 ^ (r1 & 7)) * 8)) = b1g[g];
        }
        __syncthreads();
#pragma unroll
        for (int kk = 0; kk < 2; ++kk) {
            int slot = kk * 4 + lk;
            int off = (slot ^ sw) * 8;
            bs8 a0 = *(const bs8*)(Ash + (wr * 32 + la) * 64      + off);
            bs8 a1 = *(const bs8*)(Ash + (wr * 32 + 16 + la) * 64 + off);
#pragma unroll
            for (int g = 0; g < 3; ++g) {
                const short* Bg = (const short*)(smem + 8192 + g * 8192);
                bs8 bb0 = *(const bs8*)(Bg + (wc * 32 + la) * 64      + off);
                bs8 bb1 = *(const bs8*)(Bg + (wc * 32 + 16 + la) * 64 + off);
                acc[g][0][0] = __builtin_amdgcn_mfma_f32_16x16x32_bf16(a0, bb0, acc[g][0][0], 0, 0, 0);
                acc[g][0][1] = __builtin_amdgcn_mfma_f32_16x16x32_bf16(a0, bb1, acc[g][0][1], 0, 0, 0);
                acc[g][1][0] = __builtin_amdgcn_mfma_f32_16x16x32_bf16(a1, bb0, acc[g][1][0], 0, 0, 0);
                acc[g][1][1] = __builtin_amdgcn_mfma_f32_16x16x32_bf16(a1, bb1, acc[g][1][1], 0, 0, 0);
            }
        }
    }

    const int rowb = (lane >> 4) * 4, coln = lane & 15;
#pragma unroll
    for (int i = 0; i < 2; ++i)
#pragma unroll
    for (int r = 0; r < 4; ++r) {
        int row = brow + wr * 32 + i * 16 + rowb + r;
        int sp = spk[row];
#pragma unroll
        for (int j = 0; j < 2; ++j) {
            int col = bn * 64 + wc * 32 + j * 16 + coln;   // 0..511
            const float* gib = gi_p + (size_t)row * 1536;
            const float* ghb = gh_p + (size_t)row * 1536;
            float gr_ = sigmoidf_(acc[0][i][j][r] + gib[col] + bp_ih[col] + ghb[col] + bp_hh[col]);
            float gz  = sigmoidf_(acc[1][i][j][r] + gib[512 + col] + bp_ih[512 + col] + ghb[512 + col] + bp_hh[512 + col]);
            float gn  = tanhf(acc[2][i][j][r] + gib[1024 + col] + bp_ih[1024 + col] + gr_ * (ghb[1024 + col] + bp_hh[1024 + col]));
            float o = (1.0f - gz) * gn + gz * sel0[(size_t)row * SS + col];
            par_bf[(size_t)row * SS + col] = f2bf(o);
            speaker_out[((size_t)row * PP + sp) * SS + col] = o;
        }
    }
}

// ---------------------------------------------------------------------------
// k_tailB: blocks [0,16): parties@We_ih 3-gate + emotion-GRU epilogue.
//          blocks [16,1040): speaker0 copy skipping selected rows.
// ---------------------------------------------------------------------------
#define T2G 16
__global__ __launch_bounds__(256) void k_tailB(
        const short* __restrict__ par_bf, const short* __restrict__ We_ih_bf,
        const float* __restrict__ gh_e,
        const float* __restrict__ be_ih, const float* __restrict__ be_hh,
        const float* __restrict__ emotion0, float* __restrict__ emotion_out,
        const float* __restrict__ sp0, const int* __restrict__ spk,
        float* __restrict__ speaker_out) {
    __shared__ __align__(16) char smem[32768];
    int bid = blockIdx.x, tid = threadIdx.x;
    if (bid >= T2G) {
        size_t i = ((size_t)(bid - T2G) * 256 + tid) * 4;   // over B*P*S
        int b = (int)(i >> 12);
        int p = (int)(i >> 9) & 7;
        if (p != spk[b]) *(float4*)(speaker_out + i) = *(const float4*)(sp0 + i);
        return;
    }

    short* Ash = (short*)smem;

    int bm = bid >> 2, bn = bid & 3;
    int brow = bm * 64;

    const int lane = tid & 63, wid = tid >> 6;
    const int wr = wid >> 1, wc = wid & 1;
    const int r0 = tid >> 3, c0 = tid & 7;
    const int r1 = r0 + 32;
    const int la = lane & 15, lk = lane >> 4;
    const int sw = la & 7;

    f32x4 acc[3][2][2] = {};

    for (int k0 = 0; k0 < 512; k0 += 64) {
        bs8 ah0 = *(const bs8*)(par_bf + (size_t)(brow + r0) * 512 + k0 + c0 * 8);
        bs8 ah1 = *(const bs8*)(par_bf + (size_t)(brow + r1) * 512 + k0 + c0 * 8);
        bs8 b0g[3], b1g[3];
#pragma unroll
        for (int g = 0; g < 3; ++g) {
            b0g[g] = *(const bs8*)(We_ih_bf + (size_t)(g * 256 + bn * 64 + r0) * 512 + k0 + c0 * 8);
            b1g[g] = *(const bs8*)(We_ih_bf + (size_t)(g * 256 + bn * 64 + r1) * 512 + k0 + c0 * 8);
        }
        __syncthreads();
        *(bs8*)(Ash + r0 * 64 + ((c0 ^ (r0 & 7)) * 8)) = ah0;
        *(bs8*)(Ash + r1 * 64 + ((c0 ^ (r1 & 7)) * 8)) = ah1;
#pragma unroll
        for (int g = 0; g < 3; ++g) {
            short* Bg = (short*)(smem + 8192 + g * 8192);
            *(bs8*)(Bg + r0 * 64 + ((c0 ^ (r0 & 7)) * 8)) = b0g[g];
            *(bs8*)(Bg + r1 * 64 + ((c0 ^ (r1 & 7)) * 8)) = b1g[g];
        }
        __syncthreads();
#pragma unroll
        for (int kk = 0; kk < 2; ++kk) {
            int slot = kk * 4 + lk;
            int off = (slot ^ sw) * 8;
            bs8 a0 = *(const bs8*)(Ash + (wr * 32 + la) * 64      + off);
            bs8 a1 = *(const bs8*)(Ash + (wr * 32 + 16 + la) * 64 + off);
#pragma unroll
            for (int g = 0; g < 3; ++g) {
                const short* Bg = (const short*)(smem + 8192 + g * 8192);
                bs8 bb0 = *(const bs8*)(Bg + (wc * 32 + la) * 64      + off);
                bs8 bb1 = *(const bs8*)(Bg + (wc * 32 + 16 + la) * 64 + off);
                acc[g][0][0] = __builtin_amdgcn_mfma_f32_16x16x32_bf16(a0, bb0, acc[g][0][0], 0, 0, 0);
                acc[g][0][1] = __builtin_amdgcn_mfma_f32_16x16x32_bf16(a0, bb1, acc[g][0][1], 0, 0, 0);
                acc[g][1][0] = __builtin_amdgcn_mfma_f32_16x16x32_bf16(a1, bb0, acc[g][1][0], 0, 0, 0);
                acc[g][1][1] = __builtin_amdgcn_mfma_f32_16x16x32_bf16(a1, bb1, acc[g][1][1], 0, 0, 0);
            }
        }
    }

    const int rowb = (lane >> 4) * 4, coln = lane & 15;
#pragma unroll
    for (int i = 0; i < 2; ++i)
#pragma unroll
    for (int r = 0; r < 4; ++r) {
        int row = brow + wr * 32 + i * 16 + rowb + r;
#pragma unroll
        for (int j = 0; j < 2; ++j) {
            int col = bn * 64 + wc * 32 + j * 16 + coln;   // 0..255
            const float* ghb = gh_e + (size_t)row * 768;
            float gr_ = sigmoidf_(acc[0][i][j][r] + be_ih[col] + ghb[col] + be_hh[col]);
            float gz  = sigmoidf_(acc[1][i][j][r] + be_ih[256 + col] + ghb[256 + col] + be_hh[256 + col]);
            float gn  = tanhf(acc[2][i][j][r] + be_ih[512 + col] + gr_ * (ghb[512 + col] + be_hh[512 + col]));
            emotion_out[(size_t)row * EE + col] = (1.0f - gz) * gn + gz * emotion0[(size_t)row * EE + col];
        }
    }
}

// ---------------------------------------------------------------------------
extern "C" void kernel_launch(void* const* d_in, const int* in_sizes, int n_in,
                              void* d_out, int out_size, void* d_ws, size_t ws_size,
                              hipStream_t stream) {
    const float* feature_ = (const float*)d_in[0];
    const float* mask     = (const float*)d_in[1];
    const float* ghist    = (const float*)d_in[2];
    const float* speaker0 = (const float*)d_in[3];
    const float* emotion0 = (const float*)d_in[4];
    const float* Wg_ih    = (const float*)d_in[5];
    const float* Wg_hh    = (const float*)d_in[6];
    const float* bg_ih    = (const float*)d_in[7];
    const float* bg_hh    = (const float*)d_in[8];
    const float* Wp_ih    = (const float*)d_in[9];
    const float* Wp_hh    = (const float*)d_in[10];
    const float* bp_ih    = (const float*)d_in[11];
    const float* bp_hh    = (const float*)d_in[12];
    const float* We_ih    = (const float*)d_in[13];
    const float* We_hh    = (const float*)d_in[14];
    const float* be_ih    = (const float*)d_in[15];
    const float* be_hh    = (const float*)d_in[16];
    const float* attn_W   = (const float*)d_in[17];

    float* out = (float*)d_out;
    float* emotion_out = out;
    float* global_out  = out + (size_t)BB * EE;
    float* speaker_out = global_out + (size_t)BB * GG;

    char* cur = (char*)d_ws;
    short* Wbf     = (short*)cur; cur += (size_t)WTOT * 2;
    short* xg      = (short*)cur; cur += (size_t)BB * 1536 * 2;
    short* hg_bf   = (short*)cur; cur += (size_t)BB * GG * 2;
    short* emo_bf  = (short*)cur; cur += (size_t)BB * EE * 2;
    short* sel0_bf = (short*)cur; cur += (size_t)BB * SS * 2;
    short* par_bf  = (short*)cur; cur += (size_t)BB * SS * 2;

    float* sel0    = (float*)cur; cur += (size_t)BB * SS * 4;
    float* x_      = (float*)cur; cur += (size_t)BB * GG * 4;
    float* ctxp    = (float*)cur; cur += (size_t)2048 * GG * 4;
    float2* msb    = (float2*)cur; cur += (size_t)2048 * 8;
    float* gi_g    = (float*)cur; cur += (size_t)BB * 3 * GG * 4;
    float* gh_g    = (float*)cur; cur += (size_t)BB * 3 * GG * 4;
    float* gi_p    = (float*)cur; cur += (size_t)BB * 3 * SS * 4;
    float* gh_p    = (float*)cur; cur += (size_t)BB * 3 * SS * 4;
    float* gh_e    = (float*)cur; cur += (size_t)BB * 3 * EE * 4;
    int*   spk     = (int*)cur;   cur += 256 * 4;

    const float* h_g = ghist + (size_t)(TT - 1) * BB * GG;

    short* Wg_ih_bf = Wbf + OWG_IH;
    short* Wg_hh_bf = Wbf + OWG_HH;
    short* Wp_ih_bf = Wbf + OWP_IH;
    short* Wp_hh_bf = Wbf + OWP_HH;
    short* We_ih_bf = Wbf + OWE_IH;
    short* We_hh_bf = Wbf + OWE_HH;

    // 1) conversions + gather + x_ split GEMM (independent 32 blocks)
    k_mega<<<MCE, 256, 0, stream>>>(Wg_ih, Wg_hh, Wp_ih, Wp_hh, We_ih, We_hh,
                                    attn_W, feature_, h_g, emotion0, mask, speaker0,
                                    Wbf, xg, hg_bf, emo_bf, sel0_bf, sel0, spk, x_);

    // 2) k_main: 432 GEMM blocks (first) + 2048 flash-attention blocks
    GBatch gb;
    gb.d[0] = { xg, xg, Wg_ih_bf, gi_g, 1536, 1536, 1536, 1536, 0, 3*GG, 1536, 24 };
    gb.d[1] = { hg_bf, hg_bf, Wg_hh_bf, gh_g, GG, GG, GG, GG, 0, 3*GG, GG, 24 };
    gb.d[2] = { sel0_bf, sel0_bf, Wp_hh_bf, gh_p, SS, SS, SS, SS, 0, 3*SS, SS, 24 };
    gb.d[3] = { emo_bf, emo_bf, We_hh_bf, gh_e, EE, EE, EE, EE, 0, 3*EE, EE, 12 };
    gb.d[4] = { xg, xg, Wp_ih_bf, gi_p, 1536, 1536, 1536, 1536, 0, 3*SS, FF, 24 };
    gb.start[0] = 0;  gb.start[1] = 96;  gb.start[2] = 192;
    gb.start[3] = 288; gb.start[4] = 336; gb.start[5] = 432;
    gb.ng = 5;
    k_main<<<432 + 2048, 256, 0, stream>>>(gb, x_, ghist, ctxp, msb);

    // 3) tailA: flash merge + parties 3-gate GEMM/GRU + scatter; global GRU fill
    k_tailA<<<T1G + (BB * GG) / 256, 256, 0, stream>>>(
        ctxp, msb, Wp_ih_bf, gi_p, gh_p, bp_ih, bp_hh, sel0, spk,
        par_bf, speaker_out,
        gi_g, gh_g, bg_ih, bg_hh, h_g, global_out);

    // 4) tailB: emotion 3-gate GEMM/GRU; speaker skip-copy fill
    k_tailB<<<T2G + (BB * PP * SS) / 4 / 256, 256, 0, stream>>>(
        par_bf, We_ih_bf, gh_e, be_ih, be_hh, emotion0, emotion_out,
        speaker0, spk, speaker_out);
}

// Round 10
// 112.495 us; speedup vs baseline: 1.2424x; 1.2424x over previous
//
#include <hip/hip_runtime.h>
#include <hip/hip_bf16.h>
#include <math.h>

#define BB 256
#define FF 1024
#define GG 512
#define SS 512
#define EE 256
#define PP 8
#define TT 256

typedef __attribute__((ext_vector_type(8))) short bs8;     // 8 bf16
typedef __attribute__((ext_vector_type(4))) float f32x4;

__device__ __forceinline__ float sigmoidf_(float x) { return 1.0f / (1.0f + expf(-x)); }

__device__ __forceinline__ short f2bf(float f) {
    union { float f; unsigned u; } v; v.f = f;
    unsigned r = v.u + 0x7FFFu + ((v.u >> 16) & 1u);   // RNE
    return (short)(r >> 16);
}

union BPack { bs8 s; __hip_bfloat162 h[4]; };

__device__ __forceinline__ bs8 ld8cvt(const float* p) {
    float4 a = *(const float4*)p, b = *(const float4*)(p + 4);
    BPack u;
    u.h[0] = __float22bfloat162_rn({a.x, a.y});
    u.h[1] = __float22bfloat162_rn({a.z, a.w});
    u.h[2] = __float22bfloat162_rn({b.x, b.y});
    u.h[3] = __float22bfloat162_rn({b.z, b.w});
    return u.s;
}
__device__ __forceinline__ void ld8split(const float* p, bs8& ho, bs8& lo) {
    float4 a = *(const float4*)p, b = *(const float4*)(p + 4);
    float v[8] = {a.x, a.y, a.z, a.w, b.x, b.y, b.z, b.w};
    BPack uh, ul;
#pragma unroll
    for (int j = 0; j < 4; ++j) {
        __hip_bfloat162 h2 = __float22bfloat162_rn({v[2*j], v[2*j+1]});
        uh.h[j] = h2;
        float r0 = v[2*j]   - __low2float(h2);
        float r1 = v[2*j+1] - __high2float(h2);
        ul.h[j] = __float22bfloat162_rn({r0, r1});
    }
    ho = uh.s; lo = ul.s;
}

// ---------------------------------------------------------------------------
// W slab layout (elements)
// ---------------------------------------------------------------------------
#define OWG_IH 0L
#define OWG_HH 2359296L
#define OWP_IH 3145728L
#define OWP_HH 5505024L
#define OWE_IH 6291456L
#define OWE_HH 6684672L
#define WTOT   6881280L

// ---------------------------------------------------------------------------
// k_xgemm: x_ = feature @ attn_W^T, split hi/lo, fp32-staged. 32 blocks.
// ---------------------------------------------------------------------------
__global__ __launch_bounds__(256) void k_xgemm(const float* __restrict__ feature_,
                                               const float* __restrict__ attn_W,
                                               float* __restrict__ x_) {
    __shared__ __align__(16) short Ash[4096], Asl[4096], Bsh[4096], Bsl[4096];
    int local = blockIdx.x;
    int bm = local >> 3, bn = local & 7;
    const int tid = threadIdx.x;
    const int lane = tid & 63, wid = tid >> 6;
    const int wr = wid >> 1, wc = wid & 1;
    const int r0 = tid >> 3, c0 = tid & 7;
    const int r1 = r0 + 32;
    const int la = lane & 15, lk = lane >> 4;
    const int sw = la & 7;

    f32x4 acc[2][2] = {};
    for (int k0 = 0; k0 < FF; k0 += 64) {
        bs8 ah0, ah1, bh0, bh1, al0, al1, bl0, bl1;
        ld8split(feature_ + (size_t)(bm * 64 + r0) * FF + k0 + c0 * 8, ah0, al0);
        ld8split(feature_ + (size_t)(bm * 64 + r1) * FF + k0 + c0 * 8, ah1, al1);
        ld8split(attn_W   + (size_t)(bn * 64 + r0) * FF + k0 + c0 * 8, bh0, bl0);
        ld8split(attn_W   + (size_t)(bn * 64 + r1) * FF + k0 + c0 * 8, bh1, bl1);
        __syncthreads();
        *(bs8*)(Ash + r0 * 64 + ((c0 ^ (r0 & 7)) * 8)) = ah0;
        *(bs8*)(Ash + r1 * 64 + ((c0 ^ (r1 & 7)) * 8)) = ah1;
        *(bs8*)(Asl + r0 * 64 + ((c0 ^ (r0 & 7)) * 8)) = al0;
        *(bs8*)(Asl + r1 * 64 + ((c0 ^ (r1 & 7)) * 8)) = al1;
        *(bs8*)(Bsh + r0 * 64 + ((c0 ^ (r0 & 7)) * 8)) = bh0;
        *(bs8*)(Bsh + r1 * 64 + ((c0 ^ (r1 & 7)) * 8)) = bh1;
        *(bs8*)(Bsl + r0 * 64 + ((c0 ^ (r0 & 7)) * 8)) = bl0;
        *(bs8*)(Bsl + r1 * 64 + ((c0 ^ (r1 & 7)) * 8)) = bl1;
        __syncthreads();
#pragma unroll
        for (int kk = 0; kk < 2; ++kk) {
            int slot = kk * 4 + lk;
            int off = (slot ^ sw) * 8;
            bs8 a0 = *(const bs8*)(Ash + (wr * 32 + la) * 64      + off);
            bs8 a1 = *(const bs8*)(Ash + (wr * 32 + 16 + la) * 64 + off);
            bs8 x0 = *(const bs8*)(Asl + (wr * 32 + la) * 64      + off);
            bs8 x1 = *(const bs8*)(Asl + (wr * 32 + 16 + la) * 64 + off);
            bs8 b0 = *(const bs8*)(Bsh + (wc * 32 + la) * 64      + off);
            bs8 b1 = *(const bs8*)(Bsh + (wc * 32 + 16 + la) * 64 + off);
            bs8 y0 = *(const bs8*)(Bsl + (wc * 32 + la) * 64      + off);
            bs8 y1 = *(const bs8*)(Bsl + (wc * 32 + 16 + la) * 64 + off);
            acc[0][0] = __builtin_amdgcn_mfma_f32_16x16x32_bf16(a0, b0, acc[0][0], 0, 0, 0);
            acc[0][0] = __builtin_amdgcn_mfma_f32_16x16x32_bf16(a0, y0, acc[0][0], 0, 0, 0);
            acc[0][0] = __builtin_amdgcn_mfma_f32_16x16x32_bf16(x0, b0, acc[0][0], 0, 0, 0);
            acc[0][1] = __builtin_amdgcn_mfma_f32_16x16x32_bf16(a0, b1, acc[0][1], 0, 0, 0);
            acc[0][1] = __builtin_amdgcn_mfma_f32_16x16x32_bf16(a0, y1, acc[0][1], 0, 0, 0);
            acc[0][1] = __builtin_amdgcn_mfma_f32_16x16x32_bf16(x0, b1, acc[0][1], 0, 0, 0);
            acc[1][0] = __builtin_amdgcn_mfma_f32_16x16x32_bf16(a1, b0, acc[1][0], 0, 0, 0);
            acc[1][0] = __builtin_amdgcn_mfma_f32_16x16x32_bf16(a1, y0, acc[1][0], 0, 0, 0);
            acc[1][0] = __builtin_amdgcn_mfma_f32_16x16x32_bf16(x1, b0, acc[1][0], 0, 0, 0);
            acc[1][1] = __builtin_amdgcn_mfma_f32_16x16x32_bf16(a1, b1, acc[1][1], 0, 0, 0);
            acc[1][1] = __builtin_amdgcn_mfma_f32_16x16x32_bf16(a1, y1, acc[1][1], 0, 0, 0);
            acc[1][1] = __builtin_amdgcn_mfma_f32_16x16x32_bf16(x1, b1, acc[1][1], 0, 0, 0);
        }
    }
    const int rowb = (lane >> 4) * 4, coln = lane & 15;
#pragma unroll
    for (int i = 0; i < 2; ++i)
#pragma unroll
    for (int j = 0; j < 2; ++j)
#pragma unroll
    for (int r = 0; r < 4; ++r) {
        int row = bm * 64 + wr * 32 + i * 16 + rowb + r;
        int col = bn * 64 + wc * 32 + j * 16 + coln;
        x_[(size_t)row * GG + col] = acc[i][j][r];
    }
}

// ---------------------------------------------------------------------------
// k_stream: [0,2048) flash-attention partials; then pure-streaming fill:
//   weight conv (3360), feature->xg (128), h_g (64), emotion0 (32),
//   gather (256), speaker copy (1024).  All HBM-bound, no syncs in fill.
// ---------------------------------------------------------------------------
#define SA_ATTN 2048
#define SB_W    (SA_ATTN + 3360)
#define SB_XG   (SB_W + 128)
#define SB_HG   (SB_XG + 64)
#define SB_EMO  (SB_HG + 32)
#define SB_GATH (SB_EMO + 256)
#define SB_END  (SB_GATH + 1024)

__global__ __launch_bounds__(256) void k_stream(
        const float* __restrict__ x_, const float* __restrict__ gh,
        float* __restrict__ ctxp, float2* __restrict__ msb,
        const float* __restrict__ Wg_ih, const float* __restrict__ Wg_hh,
        const float* __restrict__ Wp_ih, const float* __restrict__ Wp_hh,
        const float* __restrict__ We_ih, const float* __restrict__ We_hh,
        const float* __restrict__ feature_, const float* __restrict__ h_g,
        const float* __restrict__ emotion0,
        const float* __restrict__ mask, const float* __restrict__ sp0,
        short* __restrict__ Wbf, short* __restrict__ xg,
        short* __restrict__ hg_bf, short* __restrict__ emo_bf,
        short* __restrict__ sel0_bf, float* __restrict__ sel0,
        int* __restrict__ spk, float* __restrict__ speaker_out) {
    __shared__ __align__(16) char smem[8256];
    int blk = blockIdx.x, tid = threadIdx.x;

    if (blk < SA_ATTN) {
        int b = blk & (BB - 1), ch = blk >> 8;
        int w = tid >> 6, lane = tid & 63;
        float (*part)[GG] = (float(*)[GG])smem;
        float* wm = (float*)(smem + 8192);
        float* ws = wm + 4;

        const float* xb = x_ + (size_t)b * GG + lane * 8;
        float4 xa = *(const float4*)xb;
        float4 xc = *(const float4*)(xb + 4);

        float m = -INFINITY, s = 0.f;
        float acc[8] = {};
        int t0 = ch * 32 + w * 8;
#pragma unroll
        for (int it = 0; it < 8; ++it) {
            int t = t0 + it;
            const float* row = gh + ((size_t)t * BB + b) * GG + lane * 8;
            float4 v1 = *(const float4*)row;
            float4 v2 = *(const float4*)(row + 4);
            float p = v1.x*xa.x + v1.y*xa.y + v1.z*xa.z + v1.w*xa.w
                    + v2.x*xc.x + v2.y*xc.y + v2.z*xc.z + v2.w*xc.w;
#pragma unroll
            for (int off = 32; off; off >>= 1) p += __shfl_xor(p, off);
            float nm = fmaxf(m, p);
            float scale = expf(m - nm);
            float e = expf(p - nm);
            s = s * scale + e;
            acc[0] = acc[0]*scale + e*v1.x; acc[1] = acc[1]*scale + e*v1.y;
            acc[2] = acc[2]*scale + e*v1.z; acc[3] = acc[3]*scale + e*v1.w;
            acc[4] = acc[4]*scale + e*v2.x; acc[5] = acc[5]*scale + e*v2.y;
            acc[6] = acc[6]*scale + e*v2.z; acc[7] = acc[7]*scale + e*v2.w;
            m = nm;
        }
        if (lane == 0) { wm[w] = m; ws[w] = s; }
        *(float4*)&part[w][lane * 8]     = make_float4(acc[0], acc[1], acc[2], acc[3]);
        *(float4*)&part[w][lane * 8 + 4] = make_float4(acc[4], acc[5], acc[6], acc[7]);
        __syncthreads();

        float M = fmaxf(fmaxf(wm[0], wm[1]), fmaxf(wm[2], wm[3]));
        float f0 = expf(wm[0] - M), f1 = expf(wm[1] - M);
        float f2 = expf(wm[2] - M), f3 = expf(wm[3] - M);
        if (tid == 0) {
            float S = ws[0]*f0 + ws[1]*f1 + ws[2]*f2 + ws[3]*f3;
            msb[blk] = make_float2(M, S);
        }
        for (int j = tid; j < GG; j += 256) {
            float r = part[0][j]*f0 + part[1][j]*f1 + part[2][j]*f2 + part[3][j]*f3;
            ctxp[(size_t)blk * GG + j] = r;
        }
    } else if (blk < SB_W) {
        long i = (long)(blk - SA_ATTN) * 2048 + tid * 8;
        const float* src; long base;
        if      (i < OWG_HH) { src = Wg_ih; base = OWG_IH; }
        else if (i < OWP_IH) { src = Wg_hh; base = OWG_HH; }
        else if (i < OWP_HH) { src = Wp_ih; base = OWP_IH; }
        else if (i < OWE_IH) { src = Wp_hh; base = OWP_HH; }
        else if (i < OWE_HH) { src = We_ih; base = OWE_IH; }
        else                 { src = We_hh; base = OWE_HH; }
        *(bs8*)(Wbf + i) = ld8cvt(src + (i - base));
    } else if (blk < SB_XG) {
        long i = (long)(blk - SB_W) * 2048 + tid * 8;
        long b = i >> 10, c = i & 1023;
        *(bs8*)(xg + b * 1536 + c) = ld8cvt(feature_ + i);
    } else if (blk < SB_HG) {
        long i = (long)(blk - SB_XG) * 2048 + tid * 8;
        *(bs8*)(hg_bf + i) = ld8cvt(h_g + i);
    } else if (blk < SB_EMO) {
        long i = (long)(blk - SB_HG) * 2048 + tid * 8;
        *(bs8*)(emo_bf + i) = ld8cvt(emotion0 + i);
    } else if (blk < SB_GATH) {
        int b = blk - SB_EMO;
        int* sid = (int*)smem;
        if (tid == 0) {
            int best = 0; float bv = mask[b * PP];
            for (int p = 1; p < PP; ++p) { float v = mask[b * PP + p]; if (v > bv) { bv = v; best = p; } }
            *sid = best; spk[b] = best;
        }
        __syncthreads();
        const float* src = sp0 + ((size_t)b * PP + *sid) * SS;
        for (int j = tid; j < SS; j += 256) {
            float v = src[j];
            sel0[(size_t)b * SS + j] = v;
            short h = f2bf(v);
            sel0_bf[(size_t)b * SS + j] = h;
            xg[(size_t)b * 1536 + FF + j] = h;
        }
    } else {
        size_t i = ((size_t)(blk - SB_GATH) * 256 + tid) * 4;
        *(float4*)(speaker_out + i) = *(const float4*)(sp0 + i);
    }
}

// ---------------------------------------------------------------------------
// Batched bf16 MFMA GEMM (non-split; flags 1 = accumulate).
// ---------------------------------------------------------------------------
struct GDesc {
    const short *A, *A2, *W;
    float* C;
    int lda, lda2, kb, ldw, woff, ldc, K, nbn, flags;
};
struct GBatch {
    GDesc d[5];
    int start[6];
    int ng;
};

__global__ __launch_bounds__(256) void k_bgemm(GBatch gb) {
    __shared__ __align__(16) short Ash[4096], Bsh[4096];
    int bid = blockIdx.x;
    int g = 0;
    while (g + 1 < gb.ng && bid >= gb.start[g + 1]) ++g;
    GDesc d = gb.d[g];
    int local = bid - gb.start[g];
    int bn = local % d.nbn, bm = local / d.nbn;

    const int tid = threadIdx.x;
    const int lane = tid & 63, wid = tid >> 6;
    const int wr = wid >> 1, wc = wid & 1;
    const int r0 = tid >> 3, c0 = tid & 7;
    const int r1 = r0 + 32;
    const int la = lane & 15, lk = lane >> 4;
    const int sw = la & 7;

    f32x4 acc[2][2] = {};

    for (int k0 = 0; k0 < d.K; k0 += 64) {
        const short* Ab; int alda;
        if (k0 < d.kb) { Ab = d.A + k0; alda = d.lda; }
        else           { Ab = d.A2 + (k0 - d.kb); alda = d.lda2; }
        bs8 ah0 = *(const bs8*)(Ab + (size_t)(bm * 64 + r0) * alda + c0 * 8);
        bs8 ah1 = *(const bs8*)(Ab + (size_t)(bm * 64 + r1) * alda + c0 * 8);
        bs8 bh0 = *(const bs8*)(d.W + (size_t)(bn * 64 + r0) * d.ldw + d.woff + k0 + c0 * 8);
        bs8 bh1 = *(const bs8*)(d.W + (size_t)(bn * 64 + r1) * d.ldw + d.woff + k0 + c0 * 8);
        __syncthreads();
        *(bs8*)(Ash + r0 * 64 + ((c0 ^ (r0 & 7)) * 8)) = ah0;
        *(bs8*)(Ash + r1 * 64 + ((c0 ^ (r1 & 7)) * 8)) = ah1;
        *(bs8*)(Bsh + r0 * 64 + ((c0 ^ (r0 & 7)) * 8)) = bh0;
        *(bs8*)(Bsh + r1 * 64 + ((c0 ^ (r1 & 7)) * 8)) = bh1;
        __syncthreads();
#pragma unroll
        for (int kk = 0; kk < 2; ++kk) {
            int slot = kk * 4 + lk;
            int off = (slot ^ sw) * 8;
            bs8 a0 = *(const bs8*)(Ash + (wr * 32 + la) * 64      + off);
            bs8 a1 = *(const bs8*)(Ash + (wr * 32 + 16 + la) * 64 + off);
            bs8 b0 = *(const bs8*)(Bsh + (wc * 32 + la) * 64      + off);
            bs8 b1 = *(const bs8*)(Bsh + (wc * 32 + 16 + la) * 64 + off);
            acc[0][0] = __builtin_amdgcn_mfma_f32_16x16x32_bf16(a0, b0, acc[0][0], 0, 0, 0);
            acc[0][1] = __builtin_amdgcn_mfma_f32_16x16x32_bf16(a0, b1, acc[0][1], 0, 0, 0);
            acc[1][0] = __builtin_amdgcn_mfma_f32_16x16x32_bf16(a1, b0, acc[1][0], 0, 0, 0);
            acc[1][1] = __builtin_amdgcn_mfma_f32_16x16x32_bf16(a1, b1, acc[1][1], 0, 0, 0);
        }
    }

    const int rowb = (lane >> 4) * 4, coln = lane & 15;
    const bool accum = (d.flags & 1) != 0;
#pragma unroll
    for (int i = 0; i < 2; ++i)
#pragma unroll
    for (int j = 0; j < 2; ++j)
#pragma unroll
    for (int r = 0; r < 4; ++r) {
        int row = bm * 64 + wr * 32 + i * 16 + rowb + r;
        int col = bn * 64 + wc * 32 + j * 16 + coln;
        size_t idx = (size_t)row * d.ldc + col;
        if (accum) d.C[idx] += acc[i][j][r];
        else       d.C[idx]  = acc[i][j][r];
    }
}

// ---------------------------------------------------------------------------
// merge 8 chunk-partials per b -> ctx_bf (materialized once)
// ---------------------------------------------------------------------------
__global__ __launch_bounds__(256) void k_attnm(const float* __restrict__ ctxp,
                                               const float2* __restrict__ msb,
                                               short* __restrict__ ctx_bf) {
    int b = blockIdx.x, tid = threadIdx.x;
    float mv[8], sv[8];
    float M = -INFINITY;
#pragma unroll
    for (int c = 0; c < 8; ++c) {
        float2 t = msb[c * BB + b];
        mv[c] = t.x; sv[c] = t.y;
        M = fmaxf(M, t.x);
    }
    float S = 0.f;
    float f[8];
#pragma unroll
    for (int c = 0; c < 8; ++c) { f[c] = expf(mv[c] - M); S += sv[c] * f[c]; }
    float inv = 1.0f / S;
#pragma unroll
    for (int c = 0; c < 8; ++c) f[c] *= inv;
    for (int j = tid; j < GG; j += 256) {
        float r = 0.f;
#pragma unroll
        for (int c = 0; c < 8; ++c) r += ctxp[(size_t)(c * BB + b) * GG + j] * f[c];
        ctx_bf[(size_t)b * GG + j] = f2bf(r);
    }
}

// ---------------------------------------------------------------------------
// Fused GRU pair: [0, B*G) -> global GRU; [B*G, B*G+B*S) -> parties GRU
// (writes par_bf for the emotion GEMM, scatters fp32 into speaker_out).
// ---------------------------------------------------------------------------
__global__ __launch_bounds__(256) void k_gru2(
        const float* __restrict__ gi_g, const float* __restrict__ gh_g,
        const float* __restrict__ bg_ih, const float* __restrict__ bg_hh,
        const float* __restrict__ hg, float* __restrict__ global_out,
        const float* __restrict__ gi_p, const float* __restrict__ gh_p,
        const float* __restrict__ bp_ih, const float* __restrict__ bp_hh,
        const float* __restrict__ sel0, const int* __restrict__ spk,
        short* __restrict__ par_bf, float* __restrict__ speaker_out) {
    int idx = blockIdx.x * 256 + threadIdx.x;
    if (idx < BB * GG) {
        int b = idx / GG, j = idx - b * GG;
        const float* gib = gi_g + (size_t)b * 3 * GG;
        const float* ghb = gh_g + (size_t)b * 3 * GG;
        float r = sigmoidf_(gib[j] + bg_ih[j] + ghb[j] + bg_hh[j]);
        float z = sigmoidf_(gib[GG + j] + bg_ih[GG + j] + ghb[GG + j] + bg_hh[GG + j]);
        float n = tanhf(gib[2*GG + j] + bg_ih[2*GG + j] + r * (ghb[2*GG + j] + bg_hh[2*GG + j]));
        global_out[idx] = (1.0f - z) * n + z * hg[idx];
    } else {
        idx -= BB * GG;
        int b = idx / SS, j = idx - b * SS;
        const float* gib = gi_p + (size_t)b * 3 * SS;
        const float* ghb = gh_p + (size_t)b * 3 * SS;
        float r = sigmoidf_(gib[j] + bp_ih[j] + ghb[j] + bp_hh[j]);
        float z = sigmoidf_(gib[SS + j] + bp_ih[SS + j] + ghb[SS + j] + bp_hh[SS + j]);
        float n = tanhf(gib[2*SS + j] + bp_ih[2*SS + j] + r * (ghb[2*SS + j] + bp_hh[2*SS + j]));
        float o = (1.0f - z) * n + z * sel0[idx];
        par_bf[idx] = f2bf(o);
        speaker_out[((size_t)b * PP + spk[b]) * SS + j] = o;
    }
}

// ---------------------------------------------------------------------------
// k_tailB: 16 blocks: parties@We_ih 3-gate GEMM + emotion-GRU epilogue.
// ---------------------------------------------------------------------------
__global__ __launch_bounds__(256) void k_tailB(
        const short* __restrict__ par_bf, const short* __restrict__ We_ih_bf,
        const float* __restrict__ gh_e,
        const float* __restrict__ be_ih, const float* __restrict__ be_hh,
        const float* __restrict__ emotion0, float* __restrict__ emotion_out) {
    __shared__ __align__(16) char smem[32768];
    int bid = blockIdx.x, tid = threadIdx.x;
    short* Ash = (short*)smem;

    int bm = bid >> 2, bn = bid & 3;
    int brow = bm * 64;

    const int lane = tid & 63, wid = tid >> 6;
    const int wr = wid >> 1, wc = wid & 1;
    const int r0 = tid >> 3, c0 = tid & 7;
    const int r1 = r0 + 32;
    const int la = lane & 15, lk = lane >> 4;
    const int sw = la & 7;

    f32x4 acc[3][2][2] = {};

    for (int k0 = 0; k0 < 512; k0 += 64) {
        bs8 ah0 = *(const bs8*)(par_bf + (size_t)(brow + r0) * 512 + k0 + c0 * 8);
        bs8 ah1 = *(const bs8*)(par_bf + (size_t)(brow + r1) * 512 + k0 + c0 * 8);
        bs8 b0g[3], b1g[3];
#pragma unroll
        for (int g = 0; g < 3; ++g) {
            b0g[g] = *(const bs8*)(We_ih_bf + (size_t)(g * 256 + bn * 64 + r0) * 512 + k0 + c0 * 8);
            b1g[g] = *(const bs8*)(We_ih_bf + (size_t)(g * 256 + bn * 64 + r1) * 512 + k0 + c0 * 8);
        }
        __syncthreads();
        *(bs8*)(Ash + r0 * 64 + ((c0 ^ (r0 & 7)) * 8)) = ah0;
        *(bs8*)(Ash + r1 * 64 + ((c0 ^ (r1 & 7)) * 8)) = ah1;
#pragma unroll
        for (int g = 0; g < 3; ++g) {
            short* Bg = (short*)(smem + 8192 + g * 8192);
            *(bs8*)(Bg + r0 * 64 + ((c0 ^ (r0 & 7)) * 8)) = b0g[g];
            *(bs8*)(Bg + r1 * 64 + ((c0 ^ (r1 & 7)) * 8)) = b1g[g];
        }
        __syncthreads();
#pragma unroll
        for (int kk = 0; kk < 2; ++kk) {
            int slot = kk * 4 + lk;
            int off = (slot ^ sw) * 8;
            bs8 a0 = *(const bs8*)(Ash + (wr * 32 + la) * 64      + off);
            bs8 a1 = *(const bs8*)(Ash + (wr * 32 + 16 + la) * 64 + off);
#pragma unroll
            for (int g = 0; g < 3; ++g) {
                const short* Bg = (const short*)(smem + 8192 + g * 8192);
                bs8 bb0 = *(const bs8*)(Bg + (wc * 32 + la) * 64      + off);
                bs8 bb1 = *(const bs8*)(Bg + (wc * 32 + 16 + la) * 64 + off);
                acc[g][0][0] = __builtin_amdgcn_mfma_f32_16x16x32_bf16(a0, bb0, acc[g][0][0], 0, 0, 0);
                acc[g][0][1] = __builtin_amdgcn_mfma_f32_16x16x32_bf16(a0, bb1, acc[g][0][1], 0, 0, 0);
                acc[g][1][0] = __builtin_amdgcn_mfma_f32_16x16x32_bf16(a1, bb0, acc[g][1][0], 0, 0, 0);
                acc[g][1][1] = __builtin_amdgcn_mfma_f32_16x16x32_bf16(a1, bb1, acc[g][1][1], 0, 0, 0);
            }
        }
    }

    const int rowb = (lane >> 4) * 4, coln = lane & 15;
#pragma unroll
    for (int i = 0; i < 2; ++i)
#pragma unroll
    for (int r = 0; r < 4; ++r) {
        int row = brow + wr * 32 + i * 16 + rowb + r;
#pragma unroll
        for (int j = 0; j < 2; ++j) {
            int col = bn * 64 + wc * 32 + j * 16 + coln;   // 0..255
            const float* ghb = gh_e + (size_t)row * 768;
            float gr_ = sigmoidf_(acc[0][i][j][r] + be_ih[col] + ghb[col] + be_hh[col]);
            float gz  = sigmoidf_(acc[1][i][j][r] + be_ih[256 + col] + ghb[256 + col] + be_hh[256 + col]);
            float gn  = tanhf(acc[2][i][j][r] + be_ih[512 + col] + gr_ * (ghb[512 + col] + be_hh[512 + col]));
            emotion_out[(size_t)row * EE + col] = (1.0f - gz) * gn + gz * emotion0[(size_t)row * EE + col];
        }
    }
}

// ---------------------------------------------------------------------------
extern "C" void kernel_launch(void* const* d_in, const int* in_sizes, int n_in,
                              void* d_out, int out_size, void* d_ws, size_t ws_size,
                              hipStream_t stream) {
    const float* feature_ = (const float*)d_in[0];
    const float* mask     = (const float*)d_in[1];
    const float* ghist    = (const float*)d_in[2];
    const float* speaker0 = (const float*)d_in[3];
    const float* emotion0 = (const float*)d_in[4];
    const float* Wg_ih    = (const float*)d_in[5];
    const float* Wg_hh    = (const float*)d_in[6];
    const float* bg_ih    = (const float*)d_in[7];
    const float* bg_hh    = (const float*)d_in[8];
    const float* Wp_ih    = (const float*)d_in[9];
    const float* Wp_hh    = (const float*)d_in[10];
    const float* bp_ih    = (const float*)d_in[11];
    const float* bp_hh    = (const float*)d_in[12];
    const float* We_ih    = (const float*)d_in[13];
    const float* We_hh    = (const float*)d_in[14];
    const float* be_ih    = (const float*)d_in[15];
    const float* be_hh    = (const float*)d_in[16];
    const float* attn_W   = (const float*)d_in[17];

    float* out = (float*)d_out;
    float* emotion_out = out;
    float* global_out  = out + (size_t)BB * EE;
    float* speaker_out = global_out + (size_t)BB * GG;

    char* cur = (char*)d_ws;
    short* Wbf     = (short*)cur; cur += (size_t)WTOT * 2;
    short* xg      = (short*)cur; cur += (size_t)BB * 1536 * 2;
    short* hg_bf   = (short*)cur; cur += (size_t)BB * GG * 2;
    short* emo_bf  = (short*)cur; cur += (size_t)BB * EE * 2;
    short* sel0_bf = (short*)cur; cur += (size_t)BB * SS * 2;
    short* ctx_bf  = (short*)cur; cur += (size_t)BB * GG * 2;
    short* par_bf  = (short*)cur; cur += (size_t)BB * SS * 2;

    float* sel0    = (float*)cur; cur += (size_t)BB * SS * 4;
    float* x_      = (float*)cur; cur += (size_t)BB * GG * 4;
    float* ctxp    = (float*)cur; cur += (size_t)2048 * GG * 4;
    float2* msb    = (float2*)cur; cur += (size_t)2048 * 8;
    float* gi_g    = (float*)cur; cur += (size_t)BB * 3 * GG * 4;
    float* gh_g    = (float*)cur; cur += (size_t)BB * 3 * GG * 4;
    float* gi_p    = (float*)cur; cur += (size_t)BB * 3 * SS * 4;
    float* gh_p    = (float*)cur; cur += (size_t)BB * 3 * SS * 4;
    float* gh_e    = (float*)cur; cur += (size_t)BB * 3 * EE * 4;
    int*   spk     = (int*)cur;   cur += 256 * 4;

    const float* h_g = ghist + (size_t)(TT - 1) * BB * GG;

    short* Wg_ih_bf = Wbf + OWG_IH;
    short* Wg_hh_bf = Wbf + OWG_HH;
    short* Wp_ih_bf = Wbf + OWP_IH;
    short* Wp_hh_bf = Wbf + OWP_HH;
    short* We_ih_bf = Wbf + OWE_IH;
    short* We_hh_bf = Wbf + OWE_HH;

    // 1) x_ (independent of everything else)
    k_xgemm<<<32, 256, 0, stream>>>(feature_, attn_W, x_);

    // 2) flash-attention stream + all conversions/gather/speaker copy
    k_stream<<<SB_END, 256, 0, stream>>>(
        x_, ghist, ctxp, msb,
        Wg_ih, Wg_hh, Wp_ih, Wp_hh, We_ih, We_hh,
        feature_, h_g, emotion0, mask, speaker0,
        Wbf, xg, hg_bf, emo_bf, sel0_bf, sel0, spk, speaker_out);

    // 3) batchA: all attention-independent GEMMs
    GBatch gb;
    gb.d[0] = { xg, xg, Wg_ih_bf, gi_g, 1536, 1536, 1536, 1536, 0, 3*GG, 1536, 24, 0 };
    gb.d[1] = { hg_bf, hg_bf, Wg_hh_bf, gh_g, GG, GG, GG, GG, 0, 3*GG, GG, 24, 0 };
    gb.d[2] = { sel0_bf, sel0_bf, Wp_hh_bf, gh_p, SS, SS, SS, SS, 0, 3*SS, SS, 24, 0 };
    gb.d[3] = { emo_bf, emo_bf, We_hh_bf, gh_e, EE, EE, EE, EE, 0, 3*EE, EE, 12, 0 };
    gb.d[4] = { xg, xg, Wp_ih_bf, gi_p, 1536, 1536, 1536, 1536, 0, 3*SS, FF, 24, 0 };
    gb.start[0] = 0;   gb.start[1] = 96;  gb.start[2] = 192;
    gb.start[3] = 288; gb.start[4] = 336; gb.start[5] = 432;
    gb.ng = 5;
    k_bgemm<<<432, 256, 0, stream>>>(gb);

    // 4) merge partials -> ctx_bf (materialized once)
    k_attnm<<<BB, 256, 0, stream>>>(ctxp, msb, ctx_bf);

    // 5) gi_p += ctx @ Wp_ih[:, F:]^T   (accumulate)
    GBatch gbB;
    gbB.d[0] = { ctx_bf, ctx_bf, Wp_ih_bf, gi_p, GG, GG, GG, 1536, FF, 3*SS, GG, 24, 1 };
    gbB.start[0] = 0; gbB.start[1] = 96; gbB.ng = 1;
    k_bgemm<<<96, 256, 0, stream>>>(gbB);

    // 6) global GRU + parties GRU (+ scatter)
    k_gru2<<<(BB * GG + BB * SS) / 256, 256, 0, stream>>>(
        gi_g, gh_g, bg_ih, bg_hh, h_g, global_out,
        gi_p, gh_p, bp_ih, bp_hh, sel0, spk, par_bf, speaker_out);

    // 7) emotion 3-gate GEMM + GRU epilogue
    k_tailB<<<16, 256, 0, stream>>>(par_bf, We_ih_bf, gh_e, be_ih, be_hh,
                                    emotion0, emotion_out);
}

// Round 11
// 106.750 us; speedup vs baseline: 1.3093x; 1.0538x over previous
//
#include <hip/hip_runtime.h>
#include <hip/hip_bf16.h>
#include <math.h>

#define BB 256
#define FF 1024
#define GG 512
#define SS 512
#define EE 256
#define PP 8
#define TT 256

typedef __attribute__((ext_vector_type(8))) short bs8;     // 8 bf16
typedef __attribute__((ext_vector_type(4))) float f32x4;

__device__ __forceinline__ float sigmoidf_(float x) { return 1.0f / (1.0f + expf(-x)); }

__device__ __forceinline__ short f2bf(float f) {
    union { float f; unsigned u; } v; v.f = f;
    unsigned r = v.u + 0x7FFFu + ((v.u >> 16) & 1u);   // RNE
    return (short)(r >> 16);
}

union BPack { bs8 s; __hip_bfloat162 h[4]; };

__device__ __forceinline__ bs8 ld8cvt(const float* p) {
    float4 a = *(const float4*)p, b = *(const float4*)(p + 4);
    BPack u;
    u.h[0] = __float22bfloat162_rn({a.x, a.y});
    u.h[1] = __float22bfloat162_rn({a.z, a.w});
    u.h[2] = __float22bfloat162_rn({b.x, b.y});
    u.h[3] = __float22bfloat162_rn({b.z, b.w});
    return u.s;
}
__device__ __forceinline__ void ld8split(const float* p, bs8& ho, bs8& lo) {
    float4 a = *(const float4*)p, b = *(const float4*)(p + 4);
    float v[8] = {a.x, a.y, a.z, a.w, b.x, b.y, b.z, b.w};
    BPack uh, ul;
#pragma unroll
    for (int j = 0; j < 4; ++j) {
        __hip_bfloat162 h2 = __float22bfloat162_rn({v[2*j], v[2*j+1]});
        uh.h[j] = h2;
        float r0 = v[2*j]   - __low2float(h2);
        float r1 = v[2*j+1] - __high2float(h2);
        ul.h[j] = __float22bfloat162_rn({r0, r1});
    }
    ho = uh.s; lo = ul.s;
}

// ---------------------------------------------------------------------------
// W slab layout (elements)
// ---------------------------------------------------------------------------
#define OWG_IH 0L
#define OWG_HH 2359296L
#define OWP_IH 3145728L
#define OWP_HH 5505024L
#define OWE_IH 6291456L
#define OWE_HH 6684672L
#define WTOT   6881280L

// block-range boundaries for k_mega (identical to the 100.7us round-6 kernel)
#define MB1 3360     // W slab conv          (3360 blocks)
#define MB2 3616     // attn_W hi/lo split   (256)
#define MB3 3744     // feature -> xg/fhi/flo(128)
#define MB4 3808     // h_g -> hg_bf         (64)
#define MB5 3840     // emotion0 -> emo_bf   (32)
#define MB6 4096     // gather               (256)
#define MBE 5120     // speaker copy         (1024)

__global__ __launch_bounds__(256) void k_mega(
        const float* __restrict__ Wg_ih, const float* __restrict__ Wg_hh,
        const float* __restrict__ Wp_ih, const float* __restrict__ Wp_hh,
        const float* __restrict__ We_ih, const float* __restrict__ We_hh,
        const float* __restrict__ attn_W, const float* __restrict__ feature_,
        const float* __restrict__ h_g, const float* __restrict__ emotion0,
        const float* __restrict__ mask, const float* __restrict__ sp0,
        short* __restrict__ Wbf, short* __restrict__ awhi, short* __restrict__ awlo,
        short* __restrict__ xg, short* __restrict__ fhi, short* __restrict__ flo,
        short* __restrict__ hg_bf, short* __restrict__ emo_bf, short* __restrict__ sel0_bf,
        float* __restrict__ sel0, int* __restrict__ spk, float* __restrict__ speaker_out) {
    int blk = blockIdx.x, tid = threadIdx.x;
    if (blk < MB1) {
        long i = (long)blk * 2048 + tid * 8;
        const float* src; long base;
        if      (i < OWG_HH) { src = Wg_ih; base = OWG_IH; }
        else if (i < OWP_IH) { src = Wg_hh; base = OWG_HH; }
        else if (i < OWP_HH) { src = Wp_ih; base = OWP_IH; }
        else if (i < OWE_IH) { src = Wp_hh; base = OWP_HH; }
        else if (i < OWE_HH) { src = We_ih; base = OWE_IH; }
        else                 { src = We_hh; base = OWE_HH; }
        *(bs8*)(Wbf + i) = ld8cvt(src + (i - base));
    } else if (blk < MB2) {
        long i = (long)(blk - MB1) * 2048 + tid * 8;
        bs8 h, l;
        ld8split(attn_W + i, h, l);
        *(bs8*)(awhi + i) = h;
        *(bs8*)(awlo + i) = l;
    } else if (blk < MB3) {
        long i = (long)(blk - MB2) * 2048 + tid * 8;
        bs8 h, l;
        ld8split(feature_ + i, h, l);
        *(bs8*)(fhi + i) = h;
        *(bs8*)(flo + i) = l;
        long b = i >> 10, c = i & 1023;
        *(bs8*)(xg + b * 1536 + c) = h;
    } else if (blk < MB4) {
        long i = (long)(blk - MB3) * 2048 + tid * 8;
        *(bs8*)(hg_bf + i) = ld8cvt(h_g + i);
    } else if (blk < MB5) {
        long i = (long)(blk - MB4) * 2048 + tid * 8;
        *(bs8*)(emo_bf + i) = ld8cvt(emotion0 + i);
    } else if (blk < MB6) {
        int b = blk - MB5;
        __shared__ int sid;
        if (tid == 0) {
            int best = 0; float bv = mask[b * PP];
            for (int p = 1; p < PP; ++p) { float v = mask[b * PP + p]; if (v > bv) { bv = v; best = p; } }
            sid = best; spk[b] = best;
        }
        __syncthreads();
        const float* src = sp0 + ((size_t)b * PP + sid) * SS;
        for (int j = tid; j < SS; j += 256) {
            float v = src[j];
            sel0[(size_t)b * SS + j] = v;
            short h = f2bf(v);
            sel0_bf[(size_t)b * SS + j] = h;
            xg[(size_t)b * 1536 + FF + j] = h;
        }
    } else {
        size_t i = ((size_t)(blk - MB6) * 256 + tid) * 4;
        *(float4*)(speaker_out + i) = *(const float4*)(sp0 + i);
    }
}

// ---------------------------------------------------------------------------
// Batched bf16 MFMA GEMM (identical to the 100.7us kernel).
// flags: 1 = split (A2=A_lo, Wl=W_lo; 3-MFMA compensated), 2 = accumulate.
// ---------------------------------------------------------------------------
struct GDesc {
    const short *A, *A2, *W, *Wl;
    float* C;
    int lda, lda2, kb, ldw, woff, ldc, K, nbn, flags;
};
struct GBatch {
    GDesc d[6];
    int start[7];
    int ng;
};

__global__ __launch_bounds__(256) void k_bgemm(GBatch gb) {
    __shared__ __align__(16) short Ash[64 * 64], Bsh[64 * 64];
    __shared__ __align__(16) short Asl[64 * 64], Bsl[64 * 64];

    int bid = blockIdx.x;
    int g = 0;
    while (g + 1 < gb.ng && bid >= gb.start[g + 1]) ++g;
    GDesc d = gb.d[g];
    int local = bid - gb.start[g];
    int bn = local % d.nbn, bm = local / d.nbn;
    const bool split = (d.flags & 1) != 0;

    const int tid = threadIdx.x;
    const int lane = tid & 63, wid = tid >> 6;
    const int wr = wid >> 1, wc = wid & 1;
    const int r0 = tid >> 3, c0 = tid & 7;
    const int r1 = r0 + 32;
    const int la = lane & 15, lk = lane >> 4;
    const int sw = la & 7;

    f32x4 acc[2][2] = {};

    for (int k0 = 0; k0 < d.K; k0 += 64) {
        bs8 ah0, ah1, bh0, bh1, al0, al1, bl0, bl1;
        if (split) {
            size_t oa0 = (size_t)(bm * 64 + r0) * d.lda + k0 + c0 * 8;
            size_t oa1 = (size_t)(bm * 64 + r1) * d.lda + k0 + c0 * 8;
            size_t ow0 = (size_t)(bn * 64 + r0) * d.ldw + d.woff + k0 + c0 * 8;
            size_t ow1 = (size_t)(bn * 64 + r1) * d.ldw + d.woff + k0 + c0 * 8;
            ah0 = *(const bs8*)(d.A + oa0);  ah1 = *(const bs8*)(d.A + oa1);
            al0 = *(const bs8*)(d.A2 + oa0); al1 = *(const bs8*)(d.A2 + oa1);
            bh0 = *(const bs8*)(d.W + ow0);  bh1 = *(const bs8*)(d.W + ow1);
            bl0 = *(const bs8*)(d.Wl + ow0); bl1 = *(const bs8*)(d.Wl + ow1);
        } else {
            const short* Ab; int alda;
            if (k0 < d.kb) { Ab = d.A + k0; alda = d.lda; }
            else           { Ab = d.A2 + (k0 - d.kb); alda = d.lda2; }
            ah0 = *(const bs8*)(Ab + (size_t)(bm * 64 + r0) * alda + c0 * 8);
            ah1 = *(const bs8*)(Ab + (size_t)(bm * 64 + r1) * alda + c0 * 8);
            bh0 = *(const bs8*)(d.W + (size_t)(bn * 64 + r0) * d.ldw + d.woff + k0 + c0 * 8);
            bh1 = *(const bs8*)(d.W + (size_t)(bn * 64 + r1) * d.ldw + d.woff + k0 + c0 * 8);
        }
        __syncthreads();
        *(bs8*)(Ash + r0 * 64 + ((c0 ^ (r0 & 7)) * 8)) = ah0;
        *(bs8*)(Ash + r1 * 64 + ((c0 ^ (r1 & 7)) * 8)) = ah1;
        *(bs8*)(Bsh + r0 * 64 + ((c0 ^ (r0 & 7)) * 8)) = bh0;
        *(bs8*)(Bsh + r1 * 64 + ((c0 ^ (r1 & 7)) * 8)) = bh1;
        if (split) {
            *(bs8*)(Asl + r0 * 64 + ((c0 ^ (r0 & 7)) * 8)) = al0;
            *(bs8*)(Asl + r1 * 64 + ((c0 ^ (r1 & 7)) * 8)) = al1;
            *(bs8*)(Bsl + r0 * 64 + ((c0 ^ (r0 & 7)) * 8)) = bl0;
            *(bs8*)(Bsl + r1 * 64 + ((c0 ^ (r1 & 7)) * 8)) = bl1;
        }
        __syncthreads();
#pragma unroll
        for (int kk = 0; kk < 2; ++kk) {
            int slot = kk * 4 + lk;
            int off = (slot ^ sw) * 8;
            bs8 a0 = *(const bs8*)(Ash + (wr * 32 + la) * 64      + off);
            bs8 a1 = *(const bs8*)(Ash + (wr * 32 + 16 + la) * 64 + off);
            bs8 b0 = *(const bs8*)(Bsh + (wc * 32 + la) * 64      + off);
            bs8 b1 = *(const bs8*)(Bsh + (wc * 32 + 16 + la) * 64 + off);
            acc[0][0] = __builtin_amdgcn_mfma_f32_16x16x32_bf16(a0, b0, acc[0][0], 0, 0, 0);
            acc[0][1] = __builtin_amdgcn_mfma_f32_16x16x32_bf16(a0, b1, acc[0][1], 0, 0, 0);
            acc[1][0] = __builtin_amdgcn_mfma_f32_16x16x32_bf16(a1, b0, acc[1][0], 0, 0, 0);
            acc[1][1] = __builtin_amdgcn_mfma_f32_16x16x32_bf16(a1, b1, acc[1][1], 0, 0, 0);
            if (split) {
                bs8 xl0 = *(const bs8*)(Asl + (wr * 32 + la) * 64      + off);
                bs8 xl1 = *(const bs8*)(Asl + (wr * 32 + 16 + la) * 64 + off);
                bs8 yl0 = *(const bs8*)(Bsl + (wc * 32 + la) * 64      + off);
                bs8 yl1 = *(const bs8*)(Bsl + (wc * 32 + 16 + la) * 64 + off);
                acc[0][0] = __builtin_amdgcn_mfma_f32_16x16x32_bf16(a0, yl0, acc[0][0], 0, 0, 0);
                acc[0][0] = __builtin_amdgcn_mfma_f32_16x16x32_bf16(xl0, b0, acc[0][0], 0, 0, 0);
                acc[0][1] = __builtin_amdgcn_mfma_f32_16x16x32_bf16(a0, yl1, acc[0][1], 0, 0, 0);
                acc[0][1] = __builtin_amdgcn_mfma_f32_16x16x32_bf16(xl0, b1, acc[0][1], 0, 0, 0);
                acc[1][0] = __builtin_amdgcn_mfma_f32_16x16x32_bf16(a1, yl0, acc[1][0], 0, 0, 0);
                acc[1][0] = __builtin_amdgcn_mfma_f32_16x16x32_bf16(xl1, b0, acc[1][0], 0, 0, 0);
                acc[1][1] = __builtin_amdgcn_mfma_f32_16x16x32_bf16(a1, yl1, acc[1][1], 0, 0, 0);
                acc[1][1] = __builtin_amdgcn_mfma_f32_16x16x32_bf16(xl1, b1, acc[1][1], 0, 0, 0);
            }
        }
    }

    const int rowb = (lane >> 4) * 4, coln = lane & 15;
    const bool accum = (d.flags & 2) != 0;
#pragma unroll
    for (int i = 0; i < 2; ++i)
#pragma unroll
    for (int j = 0; j < 2; ++j)
#pragma unroll
    for (int r = 0; r < 4; ++r) {
        int row = bm * 64 + wr * 32 + i * 16 + rowb + r;
        int col = bn * 64 + wc * 32 + j * 16 + coln;
        size_t idx = (size_t)row * d.ldc + col;
        if (accum) d.C[idx] += acc[i][j][r];
        else       d.C[idx]  = acc[i][j][r];
    }
}

// ---------------------------------------------------------------------------
// Split-T flash attention (identical to the 100.7us kernel).
// ---------------------------------------------------------------------------
__global__ __launch_bounds__(256) void k_attnp(const float* __restrict__ x_,
                                               const float* __restrict__ gh,
                                               float* __restrict__ ctxp,
                                               float2* __restrict__ msb) {
    int blk = blockIdx.x;
    int b = blk & (BB - 1), ch = blk >> 8;
    int tid = threadIdx.x, w = tid >> 6, lane = tid & 63;
    __shared__ float wm[4], ws[4];
    __shared__ float part[4][GG];

    const float* xb = x_ + (size_t)b * GG + lane * 8;
    float4 xa = *(const float4*)xb;
    float4 xc = *(const float4*)(xb + 4);

    float m = -INFINITY, s = 0.f;
    float acc[8] = {};
    int t0 = ch * 32 + w * 8;
#pragma unroll
    for (int it = 0; it < 8; ++it) {
        int t = t0 + it;
        const float* row = gh + ((size_t)t * BB + b) * GG + lane * 8;
        float4 v1 = *(const float4*)row;
        float4 v2 = *(const float4*)(row + 4);
        float p = v1.x*xa.x + v1.y*xa.y + v1.z*xa.z + v1.w*xa.w
                + v2.x*xc.x + v2.y*xc.y + v2.z*xc.z + v2.w*xc.w;
#pragma unroll
        for (int off = 32; off; off >>= 1) p += __shfl_xor(p, off);
        float nm = fmaxf(m, p);
        float scale = expf(m - nm);
        float e = expf(p - nm);
        s = s * scale + e;
        acc[0] = acc[0]*scale + e*v1.x; acc[1] = acc[1]*scale + e*v1.y;
        acc[2] = acc[2]*scale + e*v1.z; acc[3] = acc[3]*scale + e*v1.w;
        acc[4] = acc[4]*scale + e*v2.x; acc[5] = acc[5]*scale + e*v2.y;
        acc[6] = acc[6]*scale + e*v2.z; acc[7] = acc[7]*scale + e*v2.w;
        m = nm;
    }
    if (lane == 0) { wm[w] = m; ws[w] = s; }
    *(float4*)&part[w][lane * 8]     = make_float4(acc[0], acc[1], acc[2], acc[3]);
    *(float4*)&part[w][lane * 8 + 4] = make_float4(acc[4], acc[5], acc[6], acc[7]);
    __syncthreads();

    float M = fmaxf(fmaxf(wm[0], wm[1]), fmaxf(wm[2], wm[3]));
    float f0 = expf(wm[0] - M), f1 = expf(wm[1] - M);
    float f2 = expf(wm[2] - M), f3 = expf(wm[3] - M);
    if (tid == 0) {
        float S = ws[0]*f0 + ws[1]*f1 + ws[2]*f2 + ws[3]*f3;
        msb[blk] = make_float2(M, S);
    }
    for (int j = tid; j < GG; j += 256) {
        float r = part[0][j]*f0 + part[1][j]*f1 + part[2][j]*f2 + part[3][j]*f3;
        ctxp[(size_t)blk * GG + j] = r;
    }
}

// merge 8 chunk-partials per b -> ctx_bf (identical to the 100.7us kernel)
__global__ __launch_bounds__(256) void k_attnm(const float* __restrict__ ctxp,
                                               const float2* __restrict__ msb,
                                               short* __restrict__ ctx_bf) {
    int b = blockIdx.x, tid = threadIdx.x;
    float mv[8], sv[8];
    float M = -INFINITY;
#pragma unroll
    for (int c = 0; c < 8; ++c) {
        float2 t = msb[c * BB + b];
        mv[c] = t.x; sv[c] = t.y;
        M = fmaxf(M, t.x);
    }
    float S = 0.f;
    float f[8];
#pragma unroll
    for (int c = 0; c < 8; ++c) { f[c] = expf(mv[c] - M); S += sv[c] * f[c]; }
    float inv = 1.0f / S;
#pragma unroll
    for (int c = 0; c < 8; ++c) f[c] *= inv;
    for (int j = tid; j < GG; j += 256) {
        float r = 0.f;
#pragma unroll
        for (int c = 0; c < 8; ++c) r += ctxp[(size_t)(c * BB + b) * GG + j] * f[c];
        ctx_bf[(size_t)b * GG + j] = f2bf(r);
    }
}

// ---------------------------------------------------------------------------
// k_tailA2: blocks [0,32): ctx_bf @ Wp_ih[:,F:] 3-gate GEMM + parties-GRU
//           epilogue (par_bf + speaker scatter). Replaces gbB + gru2-parties.
//           blocks [32,544): global GRU elementwise (fill). LDS 32KB.
// ---------------------------------------------------------------------------
#define T1G 32
__global__ __launch_bounds__(256) void k_tailA2(
        const short* __restrict__ ctx_bf, const short* __restrict__ Wp_ih_bf,
        const float* __restrict__ gi_p, const float* __restrict__ gh_p,
        const float* __restrict__ bp_ih, const float* __restrict__ bp_hh,
        const float* __restrict__ sel0, const int* __restrict__ spk,
        short* __restrict__ par_bf, float* __restrict__ speaker_out,
        const float* __restrict__ gi_g, const float* __restrict__ gh_g,
        const float* __restrict__ bg_ih, const float* __restrict__ bg_hh,
        const float* __restrict__ hg, float* __restrict__ global_out) {
    __shared__ __align__(16) short Ash[4096];
    __shared__ __align__(16) short Bs[3][4096];
    int bid = blockIdx.x, tid = threadIdx.x;
    if (bid >= T1G) {
        int idx = (bid - T1G) * 256 + tid;          // over B*G
        int b = idx / GG, j = idx - b * GG;
        const float* gib = gi_g + (size_t)b * 3 * GG;
        const float* ghb = gh_g + (size_t)b * 3 * GG;
        float r = sigmoidf_(gib[j] + bg_ih[j] + ghb[j] + bg_hh[j]);
        float z = sigmoidf_(gib[GG + j] + bg_ih[GG + j] + ghb[GG + j] + bg_hh[GG + j]);
        float n = tanhf(gib[2*GG + j] + bg_ih[2*GG + j] + r * (ghb[2*GG + j] + bg_hh[2*GG + j]));
        global_out[idx] = (1.0f - z) * n + z * hg[idx];
        return;
    }

    int bm = bid >> 3, bn = bid & 7;
    int brow = bm * 64;

    const int lane = tid & 63, wid = tid >> 6;
    const int wr = wid >> 1, wc = wid & 1;
    const int r0 = tid >> 3, c0 = tid & 7;
    const int r1 = r0 + 32;
    const int la = lane & 15, lk = lane >> 4;
    const int sw = la & 7;

    f32x4 acc[3][2][2] = {};

    for (int k0 = 0; k0 < 512; k0 += 64) {
        bs8 ah0 = *(const bs8*)(ctx_bf + (size_t)(brow + r0) * 512 + k0 + c0 * 8);
        bs8 ah1 = *(const bs8*)(ctx_bf + (size_t)(brow + r1) * 512 + k0 + c0 * 8);
        bs8 b0g[3], b1g[3];
#pragma unroll
        for (int g = 0; g < 3; ++g) {
            b0g[g] = *(const bs8*)(Wp_ih_bf + (size_t)(g * 512 + bn * 64 + r0) * 1536 + FF + k0 + c0 * 8);
            b1g[g] = *(const bs8*)(Wp_ih_bf + (size_t)(g * 512 + bn * 64 + r1) * 1536 + FF + k0 + c0 * 8);
        }
        __syncthreads();
        *(bs8*)(Ash + r0 * 64 + ((c0 ^ (r0 & 7)) * 8)) = ah0;
        *(bs8*)(Ash + r1 * 64 + ((c0 ^ (r1 & 7)) * 8)) = ah1;
#pragma unroll
        for (int g = 0; g < 3; ++g) {
            *(bs8*)(Bs[g] + r0 * 64 + ((c0 ^ (r0 & 7)) * 8)) = b0g[g];
            *(bs8*)(Bs[g] + r1 * 64 + ((c0 ^ (r1 & 7)) * 8)) = b1g[g];
        }
        __syncthreads();
#pragma unroll
        for (int kk = 0; kk < 2; ++kk) {
            int slot = kk * 4 + lk;
            int off = (slot ^ sw) * 8;
            bs8 a0 = *(const bs8*)(Ash + (wr * 32 + la) * 64      + off);
            bs8 a1 = *(const bs8*)(Ash + (wr * 32 + 16 + la) * 64 + off);
#pragma unroll
            for (int g = 0; g < 3; ++g) {
                bs8 bb0 = *(const bs8*)(Bs[g] + (wc * 32 + la) * 64      + off);
                bs8 bb1 = *(const bs8*)(Bs[g] + (wc * 32 + 16 + la) * 64 + off);
                acc[g][0][0] = __builtin_amdgcn_mfma_f32_16x16x32_bf16(a0, bb0, acc[g][0][0], 0, 0, 0);
                acc[g][0][1] = __builtin_amdgcn_mfma_f32_16x16x32_bf16(a0, bb1, acc[g][0][1], 0, 0, 0);
                acc[g][1][0] = __builtin_amdgcn_mfma_f32_16x16x32_bf16(a1, bb0, acc[g][1][0], 0, 0, 0);
                acc[g][1][1] = __builtin_amdgcn_mfma_f32_16x16x32_bf16(a1, bb1, acc[g][1][1], 0, 0, 0);
            }
        }
    }

    const int rowb = (lane >> 4) * 4, coln = lane & 15;
#pragma unroll
    for (int i = 0; i < 2; ++i)
#pragma unroll
    for (int r = 0; r < 4; ++r) {
        int row = brow + wr * 32 + i * 16 + rowb + r;
        int sp = spk[row];
#pragma unroll
        for (int j = 0; j < 2; ++j) {
            int col = bn * 64 + wc * 32 + j * 16 + coln;   // 0..511
            const float* gib = gi_p + (size_t)row * 1536;
            const float* ghb = gh_p + (size_t)row * 1536;
            float gr_ = sigmoidf_(acc[0][i][j][r] + gib[col] + bp_ih[col] + ghb[col] + bp_hh[col]);
            float gz  = sigmoidf_(acc[1][i][j][r] + gib[512 + col] + bp_ih[512 + col] + ghb[512 + col] + bp_hh[512 + col]);
            float gn  = tanhf(acc[2][i][j][r] + gib[1024 + col] + bp_ih[1024 + col] + gr_ * (ghb[1024 + col] + bp_hh[1024 + col]));
            float o = (1.0f - gz) * gn + gz * sel0[(size_t)row * SS + col];
            par_bf[(size_t)row * SS + col] = f2bf(o);
            speaker_out[((size_t)row * PP + sp) * SS + col] = o;
        }
    }
}

// ---------------------------------------------------------------------------
// k_tailB: 16 blocks: parties@We_ih 3-gate GEMM + emotion-GRU epilogue.
// ---------------------------------------------------------------------------
__global__ __launch_bounds__(256) void k_tailB(
        const short* __restrict__ par_bf, const short* __restrict__ We_ih_bf,
        const float* __restrict__ gh_e,
        const float* __restrict__ be_ih, const float* __restrict__ be_hh,
        const float* __restrict__ emotion0, float* __restrict__ emotion_out) {
    __shared__ __align__(16) short Ash[4096];
    __shared__ __align__(16) short Bs[3][4096];
    int bid = blockIdx.x, tid = threadIdx.x;

    int bm = bid >> 2, bn = bid & 3;
    int brow = bm * 64;

    const int lane = tid & 63, wid = tid >> 6;
    const int wr = wid >> 1, wc = wid & 1;
    const int r0 = tid >> 3, c0 = tid & 7;
    const int r1 = r0 + 32;
    const int la = lane & 15, lk = lane >> 4;
    const int sw = la & 7;

    f32x4 acc[3][2][2] = {};

    for (int k0 = 0; k0 < 512; k0 += 64) {
        bs8 ah0 = *(const bs8*)(par_bf + (size_t)(brow + r0) * 512 + k0 + c0 * 8);
        bs8 ah1 = *(const bs8*)(par_bf + (size_t)(brow + r1) * 512 + k0 + c0 * 8);
        bs8 b0g[3], b1g[3];
#pragma unroll
        for (int g = 0; g < 3; ++g) {
            b0g[g] = *(const bs8*)(We_ih_bf + (size_t)(g * 256 + bn * 64 + r0) * 512 + k0 + c0 * 8);
            b1g[g] = *(const bs8*)(We_ih_bf + (size_t)(g * 256 + bn * 64 + r1) * 512 + k0 + c0 * 8);
        }
        __syncthreads();
        *(bs8*)(Ash + r0 * 64 + ((c0 ^ (r0 & 7)) * 8)) = ah0;
        *(bs8*)(Ash + r1 * 64 + ((c0 ^ (r1 & 7)) * 8)) = ah1;
#pragma unroll
        for (int g = 0; g < 3; ++g) {
            *(bs8*)(Bs[g] + r0 * 64 + ((c0 ^ (r0 & 7)) * 8)) = b0g[g];
            *(bs8*)(Bs[g] + r1 * 64 + ((c0 ^ (r1 & 7)) * 8)) = b1g[g];
        }
        __syncthreads();
#pragma unroll
        for (int kk = 0; kk < 2; ++kk) {
            int slot = kk * 4 + lk;
            int off = (slot ^ sw) * 8;
            bs8 a0 = *(const bs8*)(Ash + (wr * 32 + la) * 64      + off);
            bs8 a1 = *(const bs8*)(Ash + (wr * 32 + 16 + la) * 64 + off);
#pragma unroll
            for (int g = 0; g < 3; ++g) {
                bs8 bb0 = *(const bs8*)(Bs[g] + (wc * 32 + la) * 64      + off);
                bs8 bb1 = *(const bs8*)(Bs[g] + (wc * 32 + 16 + la) * 64 + off);
                acc[g][0][0] = __builtin_amdgcn_mfma_f32_16x16x32_bf16(a0, bb0, acc[g][0][0], 0, 0, 0);
                acc[g][0][1] = __builtin_amdgcn_mfma_f32_16x16x32_bf16(a0, bb1, acc[g][0][1], 0, 0, 0);
                acc[g][1][0] = __builtin_amdgcn_mfma_f32_16x16x32_bf16(a1, bb0, acc[g][1][0], 0, 0, 0);
                acc[g][1][1] = __builtin_amdgcn_mfma_f32_16x16x32_bf16(a1, bb1, acc[g][1][1], 0, 0, 0);
            }
        }
    }

    const int rowb = (lane >> 4) * 4, coln = lane & 15;
#pragma unroll
    for (int i = 0; i < 2; ++i)
#pragma unroll
    for (int r = 0; r < 4; ++r) {
        int row = brow + wr * 32 + i * 16 + rowb + r;
#pragma unroll
        for (int j = 0; j < 2; ++j) {
            int col = bn * 64 + wc * 32 + j * 16 + coln;   // 0..255
            const float* ghb = gh_e + (size_t)row * 768;
            float gr_ = sigmoidf_(acc[0][i][j][r] + be_ih[col] + ghb[col] + be_hh[col]);
            float gz  = sigmoidf_(acc[1][i][j][r] + be_ih[256 + col] + ghb[256 + col] + be_hh[256 + col]);
            float gn  = tanhf(acc[2][i][j][r] + be_ih[512 + col] + gr_ * (ghb[512 + col] + be_hh[512 + col]));
            emotion_out[(size_t)row * EE + col] = (1.0f - gz) * gn + gz * emotion0[(size_t)row * EE + col];
        }
    }
}

// ---------------------------------------------------------------------------
extern "C" void kernel_launch(void* const* d_in, const int* in_sizes, int n_in,
                              void* d_out, int out_size, void* d_ws, size_t ws_size,
                              hipStream_t stream) {
    const float* feature_ = (const float*)d_in[0];
    const float* mask     = (const float*)d_in[1];
    const float* ghist    = (const float*)d_in[2];
    const float* speaker0 = (const float*)d_in[3];
    const float* emotion0 = (const float*)d_in[4];
    const float* Wg_ih    = (const float*)d_in[5];
    const float* Wg_hh    = (const float*)d_in[6];
    const float* bg_ih    = (const float*)d_in[7];
    const float* bg_hh    = (const float*)d_in[8];
    const float* Wp_ih    = (const float*)d_in[9];
    const float* Wp_hh    = (const float*)d_in[10];
    const float* bp_ih    = (const float*)d_in[11];
    const float* bp_hh    = (const float*)d_in[12];
    const float* We_ih    = (const float*)d_in[13];
    const float* We_hh    = (const float*)d_in[14];
    const float* be_ih    = (const float*)d_in[15];
    const float* be_hh    = (const float*)d_in[16];
    const float* attn_W   = (const float*)d_in[17];

    float* out = (float*)d_out;
    float* emotion_out = out;
    float* global_out  = out + (size_t)BB * EE;
    float* speaker_out = global_out + (size_t)BB * GG;

    char* cur = (char*)d_ws;
    short* Wbf     = (short*)cur; cur += (size_t)WTOT * 2;
    short* awhi    = (short*)cur; cur += (size_t)GG * FF * 2;
    short* awlo    = (short*)cur; cur += (size_t)GG * FF * 2;
    short* xg      = (short*)cur; cur += (size_t)BB * 1536 * 2;
    short* fhi     = (short*)cur; cur += (size_t)BB * FF * 2;
    short* flo     = (short*)cur; cur += (size_t)BB * FF * 2;
    short* hg_bf   = (short*)cur; cur += (size_t)BB * GG * 2;
    short* emo_bf  = (short*)cur; cur += (size_t)BB * EE * 2;
    short* sel0_bf = (short*)cur; cur += (size_t)BB * SS * 2;
    short* ctx_bf  = (short*)cur; cur += (size_t)BB * GG * 2;
    short* par_bf  = (short*)cur; cur += (size_t)BB * SS * 2;

    float* sel0    = (float*)cur; cur += (size_t)BB * SS * 4;
    float* x_      = (float*)cur; cur += (size_t)BB * GG * 4;
    float* ctxp    = (float*)cur; cur += (size_t)2048 * GG * 4;
    float2* msb    = (float2*)cur; cur += (size_t)2048 * 8;
    float* gi_g    = (float*)cur; cur += (size_t)BB * 3 * GG * 4;
    float* gh_g    = (float*)cur; cur += (size_t)BB * 3 * GG * 4;
    float* gi_p    = (float*)cur; cur += (size_t)BB * 3 * SS * 4;
    float* gh_p    = (float*)cur; cur += (size_t)BB * 3 * SS * 4;
    float* gh_e    = (float*)cur; cur += (size_t)BB * 3 * EE * 4;
    int*   spk     = (int*)cur;   cur += 256 * 4;

    const float* h_g = ghist + (size_t)(TT - 1) * BB * GG;

    short* Wg_ih_bf = Wbf + OWG_IH;
    short* Wg_hh_bf = Wbf + OWG_HH;
    short* Wp_ih_bf = Wbf + OWP_IH;
    short* Wp_hh_bf = Wbf + OWP_HH;
    short* We_ih_bf = Wbf + OWE_IH;
    short* We_hh_bf = Wbf + OWE_HH;

    // 1) all conversions + gather + speaker copy in one launch
    k_mega<<<MBE, 256, 0, stream>>>(Wg_ih, Wg_hh, Wp_ih, Wp_hh, We_ih, We_hh,
                                    attn_W, feature_, h_g, emotion0, mask, speaker0,
                                    Wbf, awhi, awlo, xg, fhi, flo, hg_bf, emo_bf,
                                    sel0_bf, sel0, spk, speaker_out);

    // 2) batchA: x_(split) + all attention-independent GEMMs
    GBatch gbA;
    gbA.d[0] = { fhi, flo, awhi, awlo, x_, FF, FF, FF, FF, 0, GG, FF, 8, 1 };
    gbA.d[1] = { xg, xg, Wg_ih_bf, nullptr, gi_g, 1536, 1536, 1536, 1536, 0, 3*GG, 1536, 24, 0 };
    gbA.d[2] = { hg_bf, hg_bf, Wg_hh_bf, nullptr, gh_g, GG, GG, GG, GG, 0, 3*GG, GG, 24, 0 };
    gbA.d[3] = { sel0_bf, sel0_bf, Wp_hh_bf, nullptr, gh_p, SS, SS, SS, SS, 0, 3*SS, SS, 24, 0 };
    gbA.d[4] = { emo_bf, emo_bf, We_hh_bf, nullptr, gh_e, EE, EE, EE, EE, 0, 3*EE, EE, 12, 0 };
    gbA.d[5] = { xg, xg, Wp_ih_bf, nullptr, gi_p, 1536, 1536, 1536, 1536, 0, 3*SS, FF, 24, 0 };
    gbA.start[0] = 0;   gbA.start[1] = 32;  gbA.start[2] = 128; gbA.start[3] = 224;
    gbA.start[4] = 320; gbA.start[5] = 368; gbA.start[6] = 464;
    gbA.ng = 6;
    k_bgemm<<<464, 256, 0, stream>>>(gbA);

    // 3) flash attention: single history read, 2048-block partials
    k_attnp<<<2048, 256, 0, stream>>>(x_, ghist, ctxp, msb);

    // 4) merge partials -> ctx_bf
    k_attnm<<<BB, 256, 0, stream>>>(ctxp, msb, ctx_bf);

    // 5) tailA2: ctx 3-gate GEMM + parties GRU + scatter; global GRU fill
    k_tailA2<<<T1G + (BB * GG) / 256, 256, 0, stream>>>(
        ctx_bf, Wp_ih_bf, gi_p, gh_p, bp_ih, bp_hh, sel0, spk,
        par_bf, speaker_out,
        gi_g, gh_g, bg_ih, bg_hh, h_g, global_out);

    // 6) tailB: emotion 3-gate GEMM + GRU epilogue
    k_tailB<<<16, 256, 0, stream>>>(par_bf, We_ih_bf, gh_e, be_ih, be_hh,
                                    emotion0, emotion_out);
}

// Round 12
// 93.254 us; speedup vs baseline: 1.4987x; 1.1447x over previous
//
#include <hip/hip_runtime.h>
#include <hip/hip_bf16.h>
#include <math.h>

#define BB 256
#define FF 1024
#define GG 512
#define SS 512
#define EE 256
#define PP 8
#define TT 256

typedef __attribute__((ext_vector_type(8))) short bs8;     // 8 bf16
typedef __attribute__((ext_vector_type(4))) float f32x4;

__device__ __forceinline__ float sigmoidf_(float x) { return 1.0f / (1.0f + expf(-x)); }

__device__ __forceinline__ short f2bf(float f) {
    union { float f; unsigned u; } v; v.f = f;
    unsigned r = v.u + 0x7FFFu + ((v.u >> 16) & 1u);   // RNE
    return (short)(r >> 16);
}

union BPack { bs8 s; __hip_bfloat162 h[4]; };

__device__ __forceinline__ bs8 ld8cvt(const float* p) {
    float4 a = *(const float4*)p, b = *(const float4*)(p + 4);
    BPack u;
    u.h[0] = __float22bfloat162_rn({a.x, a.y});
    u.h[1] = __float22bfloat162_rn({a.z, a.w});
    u.h[2] = __float22bfloat162_rn({b.x, b.y});
    u.h[3] = __float22bfloat162_rn({b.z, b.w});
    return u.s;
}
__device__ __forceinline__ void ld8split(const float* p, bs8& ho, bs8& lo) {
    float4 a = *(const float4*)p, b = *(const float4*)(p + 4);
    float v[8] = {a.x, a.y, a.z, a.w, b.x, b.y, b.z, b.w};
    BPack uh, ul;
#pragma unroll
    for (int j = 0; j < 4; ++j) {
        __hip_bfloat162 h2 = __float22bfloat162_rn({v[2*j], v[2*j+1]});
        uh.h[j] = h2;
        float r0 = v[2*j]   - __low2float(h2);
        float r1 = v[2*j+1] - __high2float(h2);
        ul.h[j] = __float22bfloat162_rn({r0, r1});
    }
    ho = uh.s; lo = ul.s;
}

// async global->LDS, 16B per lane, linear LDS dest (wave-uniform base + lane*16)
__device__ __forceinline__ void gload16(const short* g, short* l) {
    __builtin_amdgcn_global_load_lds(
        (const __attribute__((address_space(1))) void*)g,
        (__attribute__((address_space(3))) void*)l,
        16, 0, 0);
}

// ---------------------------------------------------------------------------
// W slab layout (elements)
// ---------------------------------------------------------------------------
#define OWG_IH 0L
#define OWG_HH 2359296L
#define OWP_IH 3145728L
#define OWP_HH 5505024L
#define OWE_IH 6291456L
#define OWE_HH 6684672L
#define WTOT   6881280L

// block-range boundaries for k_mega
#define MB1 3360     // W slab conv          (3360 blocks)
#define MB2 3616     // attn_W hi/lo split   (256)
#define MB3 3744     // feature -> xg/fhi/flo(128)
#define MB4 3808     // h_g -> hg_bf         (64)
#define MB5 3840     // emotion0 -> emo_bf   (32)
#define MB6 4096     // gather               (256)
#define MBE 5120     // speaker copy         (1024)

__global__ __launch_bounds__(256) void k_mega(
        const float* __restrict__ Wg_ih, const float* __restrict__ Wg_hh,
        const float* __restrict__ Wp_ih, const float* __restrict__ Wp_hh,
        const float* __restrict__ We_ih, const float* __restrict__ We_hh,
        const float* __restrict__ attn_W, const float* __restrict__ feature_,
        const float* __restrict__ h_g, const float* __restrict__ emotion0,
        const float* __restrict__ mask, const float* __restrict__ sp0,
        short* __restrict__ Wbf, short* __restrict__ awhi, short* __restrict__ awlo,
        short* __restrict__ xg, short* __restrict__ fhi, short* __restrict__ flo,
        short* __restrict__ hg_bf, short* __restrict__ emo_bf, short* __restrict__ sel0_bf,
        float* __restrict__ sel0, int* __restrict__ spk, float* __restrict__ speaker_out) {
    int blk = blockIdx.x, tid = threadIdx.x;
    if (blk < MB1) {
        long i = (long)blk * 2048 + tid * 8;
        const float* src; long base;
        if      (i < OWG_HH) { src = Wg_ih; base = OWG_IH; }
        else if (i < OWP_IH) { src = Wg_hh; base = OWG_HH; }
        else if (i < OWP_HH) { src = Wp_ih; base = OWP_IH; }
        else if (i < OWE_IH) { src = Wp_hh; base = OWP_HH; }
        else if (i < OWE_HH) { src = We_ih; base = OWE_IH; }
        else                 { src = We_hh; base = OWE_HH; }
        *(bs8*)(Wbf + i) = ld8cvt(src + (i - base));
    } else if (blk < MB2) {
        long i = (long)(blk - MB1) * 2048 + tid * 8;
        bs8 h, l;
        ld8split(attn_W + i, h, l);
        *(bs8*)(awhi + i) = h;
        *(bs8*)(awlo + i) = l;
    } else if (blk < MB3) {
        long i = (long)(blk - MB2) * 2048 + tid * 8;
        bs8 h, l;
        ld8split(feature_ + i, h, l);
        *(bs8*)(fhi + i) = h;
        *(bs8*)(flo + i) = l;
        long b = i >> 10, c = i & 1023;
        *(bs8*)(xg + b * 1536 + c) = h;
    } else if (blk < MB4) {
        long i = (long)(blk - MB3) * 2048 + tid * 8;
        *(bs8*)(hg_bf + i) = ld8cvt(h_g + i);
    } else if (blk < MB5) {
        long i = (long)(blk - MB4) * 2048 + tid * 8;
        *(bs8*)(emo_bf + i) = ld8cvt(emotion0 + i);
    } else if (blk < MB6) {
        int b = blk - MB5;
        __shared__ int sid;
        if (tid == 0) {
            int best = 0; float bv = mask[b * PP];
            for (int p = 1; p < PP; ++p) { float v = mask[b * PP + p]; if (v > bv) { bv = v; best = p; } }
            sid = best; spk[b] = best;
        }
        __syncthreads();
        const float* src = sp0 + ((size_t)b * PP + sid) * SS;
        for (int j = tid; j < SS; j += 256) {
            float v = src[j];
            sel0[(size_t)b * SS + j] = v;
            short h = f2bf(v);
            sel0_bf[(size_t)b * SS + j] = h;
            xg[(size_t)b * 1536 + FF + j] = h;
        }
    } else {
        size_t i = ((size_t)(blk - MB6) * 256 + tid) * 4;
        *(float4*)(speaker_out + i) = *(const float4*)(sp0 + i);
    }
}

// ---------------------------------------------------------------------------
// Batched bf16 MFMA GEMM. Staging via global_load_lds (width 16) with
// pre-swizzled GLOBAL source: LDS[row][g] = global granule g ^ (row&7),
// matching the unchanged swizzled reader. Same bytes -> same LDS slots as
// the reg-staged version: bit-identical numerics.
// flags: 1 = split (A2=A_lo, Wl=W_lo; 3-MFMA compensated), 2 = accumulate.
// ---------------------------------------------------------------------------
struct GDesc {
    const short *A, *A2, *W, *Wl;
    float* C;
    int lda, lda2, kb, ldw, woff, ldc, K, nbn, flags;
};
struct GBatch {
    GDesc d[6];
    int start[7];
    int ng;
};

__global__ __launch_bounds__(256) void k_bgemm(GBatch gb) {
    __shared__ __align__(16) short Ash[4096], Bsh[4096];
    __shared__ __align__(16) short Asl[4096], Bsl[4096];

    int bid = blockIdx.x;
    int g = 0;
    while (g + 1 < gb.ng && bid >= gb.start[g + 1]) ++g;
    GDesc d = gb.d[g];
    int local = bid - gb.start[g];
    int bn = local % d.nbn, bm = local / d.nbn;
    const bool split = (d.flags & 1) != 0;

    const int tid = threadIdx.x;
    const int lane = tid & 63, wid = tid >> 6;
    const int wr = wid >> 1, wc = wid & 1;
    const int la = lane & 15, lk = lane >> 4;
    const int sw = la & 7;

    // staging map: wave wid covers LDS bytes [wid*2048, wid*2048+2048) of each
    // 8KB tile; instr c in {0,1} covers rows wid*16 + c*8 + lane/8.
    const int srow0 = wid * 16 + (lane >> 3);
    const int srow1 = srow0 + 8;
    const int soff0 = ((lane & 7) ^ (srow0 & 7)) * 8;   // pre-swizzled granule
    const int soff1 = ((lane & 7) ^ (srow1 & 7)) * 8;
    short* Adst  = Ash + wid * 1024;
    short* Bdst  = Bsh + wid * 1024;
    short* Aldst = Asl + wid * 1024;
    short* Bldst = Bsl + wid * 1024;

    f32x4 acc[2][2] = {};

    for (int k0 = 0; k0 < d.K; k0 += 64) {
        __syncthreads();   // previous iteration's LDS reads complete
        if (split) {
            size_t oa0 = (size_t)(bm * 64 + srow0) * d.lda + k0 + soff0;
            size_t oa1 = (size_t)(bm * 64 + srow1) * d.lda + k0 + soff1;
            size_t ow0 = (size_t)(bn * 64 + srow0) * d.ldw + d.woff + k0 + soff0;
            size_t ow1 = (size_t)(bn * 64 + srow1) * d.ldw + d.woff + k0 + soff1;
            gload16(d.A  + oa0, Adst);   gload16(d.A  + oa1, Adst + 512);
            gload16(d.A2 + oa0, Aldst);  gload16(d.A2 + oa1, Aldst + 512);
            gload16(d.W  + ow0, Bdst);   gload16(d.W  + ow1, Bdst + 512);
            gload16(d.Wl + ow0, Bldst);  gload16(d.Wl + ow1, Bldst + 512);
        } else {
            const short* Ab; int alda;
            if (k0 < d.kb) { Ab = d.A + k0; alda = d.lda; }
            else           { Ab = d.A2 + (k0 - d.kb); alda = d.lda2; }
            gload16(Ab + (size_t)(bm * 64 + srow0) * alda + soff0, Adst);
            gload16(Ab + (size_t)(bm * 64 + srow1) * alda + soff1, Adst + 512);
            gload16(d.W + (size_t)(bn * 64 + srow0) * d.ldw + d.woff + k0 + soff0, Bdst);
            gload16(d.W + (size_t)(bn * 64 + srow1) * d.ldw + d.woff + k0 + soff1, Bdst + 512);
        }
        __syncthreads();   // vmcnt drain (loads landed in LDS) + barrier
#pragma unroll
        for (int kk = 0; kk < 2; ++kk) {
            int slot = kk * 4 + lk;
            int off = (slot ^ sw) * 8;
            bs8 a0 = *(const bs8*)(Ash + (wr * 32 + la) * 64      + off);
            bs8 a1 = *(const bs8*)(Ash + (wr * 32 + 16 + la) * 64 + off);
            bs8 b0 = *(const bs8*)(Bsh + (wc * 32 + la) * 64      + off);
            bs8 b1 = *(const bs8*)(Bsh + (wc * 32 + 16 + la) * 64 + off);
            acc[0][0] = __builtin_amdgcn_mfma_f32_16x16x32_bf16(a0, b0, acc[0][0], 0, 0, 0);
            acc[0][1] = __builtin_amdgcn_mfma_f32_16x16x32_bf16(a0, b1, acc[0][1], 0, 0, 0);
            acc[1][0] = __builtin_amdgcn_mfma_f32_16x16x32_bf16(a1, b0, acc[1][0], 0, 0, 0);
            acc[1][1] = __builtin_amdgcn_mfma_f32_16x16x32_bf16(a1, b1, acc[1][1], 0, 0, 0);
            if (split) {
                bs8 xl0 = *(const bs8*)(Asl + (wr * 32 + la) * 64      + off);
                bs8 xl1 = *(const bs8*)(Asl + (wr * 32 + 16 + la) * 64 + off);
                bs8 yl0 = *(const bs8*)(Bsl + (wc * 32 + la) * 64      + off);
                bs8 yl1 = *(const bs8*)(Bsl + (wc * 32 + 16 + la) * 64 + off);
                acc[0][0] = __builtin_amdgcn_mfma_f32_16x16x32_bf16(a0, yl0, acc[0][0], 0, 0, 0);
                acc[0][0] = __builtin_amdgcn_mfma_f32_16x16x32_bf16(xl0, b0, acc[0][0], 0, 0, 0);
                acc[0][1] = __builtin_amdgcn_mfma_f32_16x16x32_bf16(a0, yl1, acc[0][1], 0, 0, 0);
                acc[0][1] = __builtin_amdgcn_mfma_f32_16x16x32_bf16(xl0, b1, acc[0][1], 0, 0, 0);
                acc[1][0] = __builtin_amdgcn_mfma_f32_16x16x32_bf16(a1, yl0, acc[1][0], 0, 0, 0);
                acc[1][0] = __builtin_amdgcn_mfma_f32_16x16x32_bf16(xl1, b0, acc[1][0], 0, 0, 0);
                acc[1][1] = __builtin_amdgcn_mfma_f32_16x16x32_bf16(a1, yl1, acc[1][1], 0, 0, 0);
                acc[1][1] = __builtin_amdgcn_mfma_f32_16x16x32_bf16(xl1, b1, acc[1][1], 0, 0, 0);
            }
        }
    }

    const int rowb = (lane >> 4) * 4, coln = lane & 15;
    const bool accum = (d.flags & 2) != 0;
#pragma unroll
    for (int i = 0; i < 2; ++i)
#pragma unroll
    for (int j = 0; j < 2; ++j)
#pragma unroll
    for (int r = 0; r < 4; ++r) {
        int row = bm * 64 + wr * 32 + i * 16 + rowb + r;
        int col = bn * 64 + wc * 32 + j * 16 + coln;
        size_t idx = (size_t)row * d.ldc + col;
        if (accum) d.C[idx] += acc[i][j][r];
        else       d.C[idx]  = acc[i][j][r];
    }
}

// ---------------------------------------------------------------------------
// Split-T flash attention (identical to the 100.7us kernel).
// ---------------------------------------------------------------------------
__global__ __launch_bounds__(256) void k_attnp(const float* __restrict__ x_,
                                               const float* __restrict__ gh,
                                               float* __restrict__ ctxp,
                                               float2* __restrict__ msb) {
    int blk = blockIdx.x;
    int b = blk & (BB - 1), ch = blk >> 8;
    int tid = threadIdx.x, w = tid >> 6, lane = tid & 63;
    __shared__ float wm[4], ws[4];
    __shared__ float part[4][GG];

    const float* xb = x_ + (size_t)b * GG + lane * 8;
    float4 xa = *(const float4*)xb;
    float4 xc = *(const float4*)(xb + 4);

    float m = -INFINITY, s = 0.f;
    float acc[8] = {};
    int t0 = ch * 32 + w * 8;
#pragma unroll
    for (int it = 0; it < 8; ++it) {
        int t = t0 + it;
        const float* row = gh + ((size_t)t * BB + b) * GG + lane * 8;
        float4 v1 = *(const float4*)row;
        float4 v2 = *(const float4*)(row + 4);
        float p = v1.x*xa.x + v1.y*xa.y + v1.z*xa.z + v1.w*xa.w
                + v2.x*xc.x + v2.y*xc.y + v2.z*xc.z + v2.w*xc.w;
#pragma unroll
        for (int off = 32; off; off >>= 1) p += __shfl_xor(p, off);
        float nm = fmaxf(m, p);
        float scale = expf(m - nm);
        float e = expf(p - nm);
        s = s * scale + e;
        acc[0] = acc[0]*scale + e*v1.x; acc[1] = acc[1]*scale + e*v1.y;
        acc[2] = acc[2]*scale + e*v1.z; acc[3] = acc[3]*scale + e*v1.w;
        acc[4] = acc[4]*scale + e*v2.x; acc[5] = acc[5]*scale + e*v2.y;
        acc[6] = acc[6]*scale + e*v2.z; acc[7] = acc[7]*scale + e*v2.w;
        m = nm;
    }
    if (lane == 0) { wm[w] = m; ws[w] = s; }
    *(float4*)&part[w][lane * 8]     = make_float4(acc[0], acc[1], acc[2], acc[3]);
    *(float4*)&part[w][lane * 8 + 4] = make_float4(acc[4], acc[5], acc[6], acc[7]);
    __syncthreads();

    float M = fmaxf(fmaxf(wm[0], wm[1]), fmaxf(wm[2], wm[3]));
    float f0 = expf(wm[0] - M), f1 = expf(wm[1] - M);
    float f2 = expf(wm[2] - M), f3 = expf(wm[3] - M);
    if (tid == 0) {
        float S = ws[0]*f0 + ws[1]*f1 + ws[2]*f2 + ws[3]*f3;
        msb[blk] = make_float2(M, S);
    }
    for (int j = tid; j < GG; j += 256) {
        float r = part[0][j]*f0 + part[1][j]*f1 + part[2][j]*f2 + part[3][j]*f3;
        ctxp[(size_t)blk * GG + j] = r;
    }
}

// merge 8 chunk-partials per b -> ctx_bf
__global__ __launch_bounds__(256) void k_attnm(const float* __restrict__ ctxp,
                                               const float2* __restrict__ msb,
                                               short* __restrict__ ctx_bf) {
    int b = blockIdx.x, tid = threadIdx.x;
    float mv[8], sv[8];
    float M = -INFINITY;
#pragma unroll
    for (int c = 0; c < 8; ++c) {
        float2 t = msb[c * BB + b];
        mv[c] = t.x; sv[c] = t.y;
        M = fmaxf(M, t.x);
    }
    float S = 0.f;
    float f[8];
#pragma unroll
    for (int c = 0; c < 8; ++c) { f[c] = expf(mv[c] - M); S += sv[c] * f[c]; }
    float inv = 1.0f / S;
#pragma unroll
    for (int c = 0; c < 8; ++c) f[c] *= inv;
    for (int j = tid; j < GG; j += 256) {
        float r = 0.f;
#pragma unroll
        for (int c = 0; c < 8; ++c) r += ctxp[(size_t)(c * BB + b) * GG + j] * f[c];
        ctx_bf[(size_t)b * GG + j] = f2bf(r);
    }
}

// ---------------------------------------------------------------------------
// Fused GRU pair: [0, B*G) -> global GRU; [B*G, B*G+B*S) -> parties GRU
// ---------------------------------------------------------------------------
__global__ __launch_bounds__(256) void k_gru2(
        const float* __restrict__ gi_g, const float* __restrict__ gh_g,
        const float* __restrict__ bg_ih, const float* __restrict__ bg_hh,
        const float* __restrict__ hg, float* __restrict__ global_out,
        const float* __restrict__ gi_p, const float* __restrict__ gh_p,
        const float* __restrict__ bp_ih, const float* __restrict__ bp_hh,
        const float* __restrict__ sel0, const int* __restrict__ spk,
        short* __restrict__ par_bf, float* __restrict__ speaker_out) {
    int idx = blockIdx.x * 256 + threadIdx.x;
    if (idx < BB * GG) {
        int b = idx / GG, j = idx - b * GG;
        const float* gib = gi_g + (size_t)b * 3 * GG;
        const float* ghb = gh_g + (size_t)b * 3 * GG;
        float r = sigmoidf_(gib[j] + bg_ih[j] + ghb[j] + bg_hh[j]);
        float z = sigmoidf_(gib[GG + j] + bg_ih[GG + j] + ghb[GG + j] + bg_hh[GG + j]);
        float n = tanhf(gib[2*GG + j] + bg_ih[2*GG + j] + r * (ghb[2*GG + j] + bg_hh[2*GG + j]));
        global_out[idx] = (1.0f - z) * n + z * hg[idx];
    } else {
        idx -= BB * GG;
        int b = idx / SS, j = idx - b * SS;
        const float* gib = gi_p + (size_t)b * 3 * SS;
        const float* ghb = gh_p + (size_t)b * 3 * SS;
        float r = sigmoidf_(gib[j] + bp_ih[j] + ghb[j] + bp_hh[j]);
        float z = sigmoidf_(gib[SS + j] + bp_ih[SS + j] + ghb[SS + j] + bp_hh[SS + j]);
        float n = tanhf(gib[2*SS + j] + bp_ih[2*SS + j] + r * (ghb[2*SS + j] + bp_hh[2*SS + j]));
        float o = (1.0f - z) * n + z * sel0[idx];
        par_bf[idx] = f2bf(o);
        speaker_out[((size_t)b * PP + spk[b]) * SS + j] = o;
    }
}

// emotion GRU
__global__ __launch_bounds__(256) void k_gru(const float* __restrict__ gi, const float* __restrict__ gh,
                                             const float* __restrict__ bih, const float* __restrict__ bhh,
                                             const float* __restrict__ h,
                                             float* __restrict__ out, int H) {
    int idx = blockIdx.x * 256 + threadIdx.x;
    int b = idx / H, j = idx - b * H;
    const float* gib = gi + (size_t)b * 3 * H;
    const float* ghb = gh + (size_t)b * 3 * H;
    float r = sigmoidf_(gib[j] + bih[j] + ghb[j] + bhh[j]);
    float z = sigmoidf_(gib[H + j] + bih[H + j] + ghb[H + j] + bhh[H + j]);
    float n = tanhf(gib[2 * H + j] + bih[2 * H + j] + r * (ghb[2 * H + j] + bhh[2 * H + j]));
    out[idx] = (1.0f - z) * n + z * h[idx];
}

// ---------------------------------------------------------------------------
extern "C" void kernel_launch(void* const* d_in, const int* in_sizes, int n_in,
                              void* d_out, int out_size, void* d_ws, size_t ws_size,
                              hipStream_t stream) {
    const float* feature_ = (const float*)d_in[0];
    const float* mask     = (const float*)d_in[1];
    const float* ghist    = (const float*)d_in[2];
    const float* speaker0 = (const float*)d_in[3];
    const float* emotion0 = (const float*)d_in[4];
    const float* Wg_ih    = (const float*)d_in[5];
    const float* Wg_hh    = (const float*)d_in[6];
    const float* bg_ih    = (const float*)d_in[7];
    const float* bg_hh    = (const float*)d_in[8];
    const float* Wp_ih    = (const float*)d_in[9];
    const float* Wp_hh    = (const float*)d_in[10];
    const float* bp_ih    = (const float*)d_in[11];
    const float* bp_hh    = (const float*)d_in[12];
    const float* We_ih    = (const float*)d_in[13];
    const float* We_hh    = (const float*)d_in[14];
    const float* be_ih    = (const float*)d_in[15];
    const float* be_hh    = (const float*)d_in[16];
    const float* attn_W   = (const float*)d_in[17];

    float* out = (float*)d_out;
    float* emotion_out = out;
    float* global_out  = out + (size_t)BB * EE;
    float* speaker_out = global_out + (size_t)BB * GG;

    char* cur = (char*)d_ws;
    short* Wbf     = (short*)cur; cur += (size_t)WTOT * 2;
    short* awhi    = (short*)cur; cur += (size_t)GG * FF * 2;
    short* awlo    = (short*)cur; cur += (size_t)GG * FF * 2;
    short* xg      = (short*)cur; cur += (size_t)BB * 1536 * 2;
    short* fhi     = (short*)cur; cur += (size_t)BB * FF * 2;
    short* flo     = (short*)cur; cur += (size_t)BB * FF * 2;
    short* hg_bf   = (short*)cur; cur += (size_t)BB * GG * 2;
    short* emo_bf  = (short*)cur; cur += (size_t)BB * EE * 2;
    short* sel0_bf = (short*)cur; cur += (size_t)BB * SS * 2;
    short* ctx_bf  = (short*)cur; cur += (size_t)BB * GG * 2;
    short* par_bf  = (short*)cur; cur += (size_t)BB * SS * 2;

    float* sel0    = (float*)cur; cur += (size_t)BB * SS * 4;
    float* x_      = (float*)cur; cur += (size_t)BB * GG * 4;
    float* ctxp    = (float*)cur; cur += (size_t)2048 * GG * 4;
    float2* msb    = (float2*)cur; cur += (size_t)2048 * 8;
    float* gi_g    = (float*)cur; cur += (size_t)BB * 3 * GG * 4;
    float* gh_g    = (float*)cur; cur += (size_t)BB * 3 * GG * 4;
    float* gi_p    = (float*)cur; cur += (size_t)BB * 3 * SS * 4;
    float* gh_p    = (float*)cur; cur += (size_t)BB * 3 * SS * 4;
    float* gi_e    = (float*)cur; cur += (size_t)BB * 3 * EE * 4;
    float* gh_e    = (float*)cur; cur += (size_t)BB * 3 * EE * 4;
    int*   spk     = (int*)cur;   cur += 256 * 4;

    const float* h_g = ghist + (size_t)(TT - 1) * BB * GG;

    short* Wg_ih_bf = Wbf + OWG_IH;
    short* Wg_hh_bf = Wbf + OWG_HH;
    short* Wp_ih_bf = Wbf + OWP_IH;
    short* Wp_hh_bf = Wbf + OWP_HH;
    short* We_ih_bf = Wbf + OWE_IH;
    short* We_hh_bf = Wbf + OWE_HH;

    // 1) conversions + gather + speaker copy
    k_mega<<<MBE, 256, 0, stream>>>(Wg_ih, Wg_hh, Wp_ih, Wp_hh, We_ih, We_hh,
                                    attn_W, feature_, h_g, emotion0, mask, speaker0,
                                    Wbf, awhi, awlo, xg, fhi, flo, hg_bf, emo_bf,
                                    sel0_bf, sel0, spk, speaker_out);

    // 2) batchA: x_(split) + all attention-independent GEMMs
    GBatch gbA;
    gbA.d[0] = { fhi, flo, awhi, awlo, x_, FF, FF, FF, FF, 0, GG, FF, 8, 1 };
    gbA.d[1] = { xg, xg, Wg_ih_bf, nullptr, gi_g, 1536, 1536, 1536, 1536, 0, 3*GG, 1536, 24, 0 };
    gbA.d[2] = { hg_bf, hg_bf, Wg_hh_bf, nullptr, gh_g, GG, GG, GG, GG, 0, 3*GG, GG, 24, 0 };
    gbA.d[3] = { sel0_bf, sel0_bf, Wp_hh_bf, nullptr, gh_p, SS, SS, SS, SS, 0, 3*SS, SS, 24, 0 };
    gbA.d[4] = { emo_bf, emo_bf, We_hh_bf, nullptr, gh_e, EE, EE, EE, EE, 0, 3*EE, EE, 12, 0 };
    gbA.d[5] = { xg, xg, Wp_ih_bf, nullptr, gi_p, 1536, 1536, 1536, 1536, 0, 3*SS, FF, 24, 0 };
    gbA.start[0] = 0;   gbA.start[1] = 32;  gbA.start[2] = 128; gbA.start[3] = 224;
    gbA.start[4] = 320; gbA.start[5] = 368; gbA.start[6] = 464;
    gbA.ng = 6;
    k_bgemm<<<464, 256, 0, stream>>>(gbA);

    // 3) flash attention partials (single history read)
    k_attnp<<<2048, 256, 0, stream>>>(x_, ghist, ctxp, msb);

    // 4) merge partials -> ctx_bf
    k_attnm<<<BB, 256, 0, stream>>>(ctxp, msb, ctx_bf);

    // 5) gi_p += ctx @ Wp_ih[:, F:]^T (accumulate)
    GBatch gbB;
    gbB.d[0] = { ctx_bf, ctx_bf, Wp_ih_bf, nullptr, gi_p, GG, GG, GG, 1536, FF, 3*SS, GG, 24, 2 };
    gbB.start[0] = 0; gbB.start[1] = 96; gbB.ng = 1;
    k_bgemm<<<96, 256, 0, stream>>>(gbB);

    // 6) global GRU + parties GRU (+ scatter)
    k_gru2<<<(BB * GG + BB * SS) / 256, 256, 0, stream>>>(
        gi_g, gh_g, bg_ih, bg_hh, h_g, global_out,
        gi_p, gh_p, bp_ih, bp_hh, sel0, spk, par_bf, speaker_out);

    // 7) gi_e = parties @ We_ih^T
    GBatch gbC;
    gbC.d[0] = { par_bf, par_bf, We_ih_bf, nullptr, gi_e, SS, SS, SS, SS, 0, 3*EE, SS, 12, 0 };
    gbC.start[0] = 0; gbC.start[1] = 48; gbC.ng = 1;
    k_bgemm<<<48, 256, 0, stream>>>(gbC);

    // 8) emotion GRU
    k_gru<<<(BB * EE) / 256, 256, 0, stream>>>(gi_e, gh_e, be_ih, be_hh, emotion0, emotion_out, EE);
}

// Round 13
// 86.110 us; speedup vs baseline: 1.6231x; 1.0830x over previous
//
#include <hip/hip_runtime.h>
#include <hip/hip_bf16.h>
#include <math.h>

#define BB 256
#define FF 1024
#define GG 512
#define SS 512
#define EE 256
#define PP 8
#define TT 256

typedef __attribute__((ext_vector_type(8))) short bs8;     // 8 bf16
typedef __attribute__((ext_vector_type(4))) float f32x4;

__device__ __forceinline__ float sigmoidf_(float x) { return 1.0f / (1.0f + expf(-x)); }

__device__ __forceinline__ short f2bf(float f) {
    union { float f; unsigned u; } v; v.f = f;
    unsigned r = v.u + 0x7FFFu + ((v.u >> 16) & 1u);   // RNE
    return (short)(r >> 16);
}

union BPack { bs8 s; __hip_bfloat162 h[4]; };

__device__ __forceinline__ bs8 ld8cvt(const float* p) {
    float4 a = *(const float4*)p, b = *(const float4*)(p + 4);
    BPack u;
    u.h[0] = __float22bfloat162_rn({a.x, a.y});
    u.h[1] = __float22bfloat162_rn({a.z, a.w});
    u.h[2] = __float22bfloat162_rn({b.x, b.y});
    u.h[3] = __float22bfloat162_rn({b.z, b.w});
    return u.s;
}
__device__ __forceinline__ void ld8split(const float* p, bs8& ho, bs8& lo) {
    float4 a = *(const float4*)p, b = *(const float4*)(p + 4);
    float v[8] = {a.x, a.y, a.z, a.w, b.x, b.y, b.z, b.w};
    BPack uh, ul;
#pragma unroll
    for (int j = 0; j < 4; ++j) {
        __hip_bfloat162 h2 = __float22bfloat162_rn({v[2*j], v[2*j+1]});
        uh.h[j] = h2;
        float r0 = v[2*j]   - __low2float(h2);
        float r1 = v[2*j+1] - __high2float(h2);
        ul.h[j] = __float22bfloat162_rn({r0, r1});
    }
    ho = uh.s; lo = ul.s;
}

// async global->LDS, 16B per lane, linear LDS dest (wave-uniform base + lane*16)
__device__ __forceinline__ void gload16(const short* g, short* l) {
    __builtin_amdgcn_global_load_lds(
        (const __attribute__((address_space(1))) void*)g,
        (__attribute__((address_space(3))) void*)l,
        16, 0, 0);
}

// ---------------------------------------------------------------------------
// W slab layout (elements)
// ---------------------------------------------------------------------------
#define OWG_IH 0L
#define OWG_HH 2359296L
#define OWP_IH 3145728L
#define OWP_HH 5505024L
#define OWE_IH 6291456L
#define OWE_HH 6684672L
#define WTOT   6881280L

// block-range boundaries for k_mega
#define MB1 3360     // W slab conv          (3360 blocks)
#define MB2 3616     // attn_W hi/lo split   (256)
#define MB3 3744     // feature -> xg/fhi/flo(128)
#define MB4 3808     // h_g -> hg_bf         (64)
#define MB5 3840     // emotion0 -> emo_bf   (32)
#define MB6 4096     // gather               (256)
#define MBE 5120     // speaker copy         (1024)

__global__ __launch_bounds__(256) void k_mega(
        const float* __restrict__ Wg_ih, const float* __restrict__ Wg_hh,
        const float* __restrict__ Wp_ih, const float* __restrict__ Wp_hh,
        const float* __restrict__ We_ih, const float* __restrict__ We_hh,
        const float* __restrict__ attn_W, const float* __restrict__ feature_,
        const float* __restrict__ h_g, const float* __restrict__ emotion0,
        const float* __restrict__ mask, const float* __restrict__ sp0,
        short* __restrict__ Wbf, short* __restrict__ awhi, short* __restrict__ awlo,
        short* __restrict__ xg, short* __restrict__ fhi, short* __restrict__ flo,
        short* __restrict__ hg_bf, short* __restrict__ emo_bf, short* __restrict__ sel0_bf,
        float* __restrict__ sel0, int* __restrict__ spk, float* __restrict__ speaker_out) {
    int blk = blockIdx.x, tid = threadIdx.x;
    if (blk < MB1) {
        long i = (long)blk * 2048 + tid * 8;
        const float* src; long base;
        if      (i < OWG_HH) { src = Wg_ih; base = OWG_IH; }
        else if (i < OWP_IH) { src = Wg_hh; base = OWG_HH; }
        else if (i < OWP_HH) { src = Wp_ih; base = OWP_IH; }
        else if (i < OWE_IH) { src = Wp_hh; base = OWP_HH; }
        else if (i < OWE_HH) { src = We_ih; base = OWE_IH; }
        else                 { src = We_hh; base = OWE_HH; }
        *(bs8*)(Wbf + i) = ld8cvt(src + (i - base));
    } else if (blk < MB2) {
        long i = (long)(blk - MB1) * 2048 + tid * 8;
        bs8 h, l;
        ld8split(attn_W + i, h, l);
        *(bs8*)(awhi + i) = h;
        *(bs8*)(awlo + i) = l;
    } else if (blk < MB3) {
        long i = (long)(blk - MB2) * 2048 + tid * 8;
        bs8 h, l;
        ld8split(feature_ + i, h, l);
        *(bs8*)(fhi + i) = h;
        *(bs8*)(flo + i) = l;
        long b = i >> 10, c = i & 1023;
        *(bs8*)(xg + b * 1536 + c) = h;
    } else if (blk < MB4) {
        long i = (long)(blk - MB3) * 2048 + tid * 8;
        *(bs8*)(hg_bf + i) = ld8cvt(h_g + i);
    } else if (blk < MB5) {
        long i = (long)(blk - MB4) * 2048 + tid * 8;
        *(bs8*)(emo_bf + i) = ld8cvt(emotion0 + i);
    } else if (blk < MB6) {
        int b = blk - MB5;
        __shared__ int sid;
        if (tid == 0) {
            int best = 0; float bv = mask[b * PP];
            for (int p = 1; p < PP; ++p) { float v = mask[b * PP + p]; if (v > bv) { bv = v; best = p; } }
            sid = best; spk[b] = best;
        }
        __syncthreads();
        const float* src = sp0 + ((size_t)b * PP + sid) * SS;
        for (int j = tid; j < SS; j += 256) {
            float v = src[j];
            sel0[(size_t)b * SS + j] = v;
            short h = f2bf(v);
            sel0_bf[(size_t)b * SS + j] = h;
            xg[(size_t)b * 1536 + FF + j] = h;
        }
    } else {
        size_t i = ((size_t)(blk - MB6) * 256 + tid) * 4;
        *(float4*)(speaker_out + i) = *(const float4*)(sp0 + i);
    }
}

// ---------------------------------------------------------------------------
// Batched bf16 MFMA GEMM. global_load_lds staging (width 16), pre-swizzled
// global source, BK=128 (two 64-col chunks per stage; one barrier pair per
// 128 cols). Bit-identical bytes/order vs the BK=64 version.
// flags: 1 = split (A2=A_lo, Wl=W_lo; 3-MFMA compensated), 2 = accumulate.
// ---------------------------------------------------------------------------
struct GDesc {
    const short *A, *A2, *W, *Wl;
    float* C;
    int lda, lda2, kb, ldw, woff, ldc, K, nbn, flags;
};
struct GBatch {
    GDesc d[6];
    int start[7];
    int ng;
};

__global__ __launch_bounds__(256) void k_bgemm(GBatch gb) {
    __shared__ __align__(16) short Ash[8192], Bsh[8192];   // 64 x 128 each
    __shared__ __align__(16) short Asl[8192], Bsl[8192];

    int bid = blockIdx.x;
    int g = 0;
    while (g + 1 < gb.ng && bid >= gb.start[g + 1]) ++g;
    GDesc d = gb.d[g];
    int local = bid - gb.start[g];
    int bn = local % d.nbn, bm = local / d.nbn;
    const bool split = (d.flags & 1) != 0;

    const int tid = threadIdx.x;
    const int lane = tid & 63, wid = tid >> 6;
    const int wr = wid >> 1, wc = wid & 1;
    const int la = lane & 15, lk = lane >> 4;
    const int sw = la & 7;

    // staging map: wave wid covers rows [wid*16, wid*16+16) of the 64x128
    // tile; instr c covers rows wid*16 + c*4 + lane/16, granule lane&15.
    int srow[4], soff[4];
#pragma unroll
    for (int c = 0; c < 4; ++c) {
        srow[c] = wid * 16 + c * 4 + (lane >> 4);
        int gq = lane & 15;
        soff[c] = (gq >> 3) * 64 + (((gq & 7) ^ (srow[c] & 7)) * 8);  // pre-swizzled
    }
    short* Adst  = Ash + wid * 2048;
    short* Bdst  = Bsh + wid * 2048;
    short* Aldst = Asl + wid * 2048;
    short* Bldst = Bsl + wid * 2048;

    f32x4 acc[2][2] = {};

    for (int k0 = 0; k0 < d.K; k0 += 128) {
        __syncthreads();   // previous iteration's LDS reads complete
        if (split) {
#pragma unroll
            for (int c = 0; c < 4; ++c) {
                size_t oa = (size_t)(bm * 64 + srow[c]) * d.lda + k0 + soff[c];
                size_t ow = (size_t)(bn * 64 + srow[c]) * d.ldw + d.woff + k0 + soff[c];
                gload16(d.A  + oa, Adst  + c * 512);
                gload16(d.A2 + oa, Aldst + c * 512);
                gload16(d.W  + ow, Bdst  + c * 512);
                gload16(d.Wl + ow, Bldst + c * 512);
            }
        } else {
            const short* Ab; int alda;
            if (k0 < d.kb) { Ab = d.A + k0; alda = d.lda; }
            else           { Ab = d.A2 + (k0 - d.kb); alda = d.lda2; }
#pragma unroll
            for (int c = 0; c < 4; ++c) {
                gload16(Ab + (size_t)(bm * 64 + srow[c]) * alda + soff[c], Adst + c * 512);
                gload16(d.W + (size_t)(bn * 64 + srow[c]) * d.ldw + d.woff + k0 + soff[c], Bdst + c * 512);
            }
        }
        __syncthreads();   // vmcnt drain (loads landed in LDS) + barrier
#pragma unroll
        for (int kk = 0; kk < 4; ++kk) {
            int gran = kk * 4 + lk;                               // 0..15
            int off = (gran >> 3) * 64 + (((gran & 7) ^ sw) * 8);
            bs8 a0 = *(const bs8*)(Ash + (wr * 32 + la) * 128      + off);
            bs8 a1 = *(const bs8*)(Ash + (wr * 32 + 16 + la) * 128 + off);
            bs8 b0 = *(const bs8*)(Bsh + (wc * 32 + la) * 128      + off);
            bs8 b1 = *(const bs8*)(Bsh + (wc * 32 + 16 + la) * 128 + off);
            acc[0][0] = __builtin_amdgcn_mfma_f32_16x16x32_bf16(a0, b0, acc[0][0], 0, 0, 0);
            acc[0][1] = __builtin_amdgcn_mfma_f32_16x16x32_bf16(a0, b1, acc[0][1], 0, 0, 0);
            acc[1][0] = __builtin_amdgcn_mfma_f32_16x16x32_bf16(a1, b0, acc[1][0], 0, 0, 0);
            acc[1][1] = __builtin_amdgcn_mfma_f32_16x16x32_bf16(a1, b1, acc[1][1], 0, 0, 0);
            if (split) {
                bs8 xl0 = *(const bs8*)(Asl + (wr * 32 + la) * 128      + off);
                bs8 xl1 = *(const bs8*)(Asl + (wr * 32 + 16 + la) * 128 + off);
                bs8 yl0 = *(const bs8*)(Bsl + (wc * 32 + la) * 128      + off);
                bs8 yl1 = *(const bs8*)(Bsl + (wc * 32 + 16 + la) * 128 + off);
                acc[0][0] = __builtin_amdgcn_mfma_f32_16x16x32_bf16(a0, yl0, acc[0][0], 0, 0, 0);
                acc[0][0] = __builtin_amdgcn_mfma_f32_16x16x32_bf16(xl0, b0, acc[0][0], 0, 0, 0);
                acc[0][1] = __builtin_amdgcn_mfma_f32_16x16x32_bf16(a0, yl1, acc[0][1], 0, 0, 0);
                acc[0][1] = __builtin_amdgcn_mfma_f32_16x16x32_bf16(xl0, b1, acc[0][1], 0, 0, 0);
                acc[1][0] = __builtin_amdgcn_mfma_f32_16x16x32_bf16(a1, yl0, acc[1][0], 0, 0, 0);
                acc[1][0] = __builtin_amdgcn_mfma_f32_16x16x32_bf16(xl1, b0, acc[1][0], 0, 0, 0);
                acc[1][1] = __builtin_amdgcn_mfma_f32_16x16x32_bf16(a1, yl1, acc[1][1], 0, 0, 0);
                acc[1][1] = __builtin_amdgcn_mfma_f32_16x16x32_bf16(xl1, b1, acc[1][1], 0, 0, 0);
            }
        }
    }

    const int rowb = (lane >> 4) * 4, coln = lane & 15;
    const bool accum = (d.flags & 2) != 0;
#pragma unroll
    for (int i = 0; i < 2; ++i)
#pragma unroll
    for (int j = 0; j < 2; ++j)
#pragma unroll
    for (int r = 0; r < 4; ++r) {
        int row = bm * 64 + wr * 32 + i * 16 + rowb + r;
        int col = bn * 64 + wc * 32 + j * 16 + coln;
        size_t idx = (size_t)row * d.ldc + col;
        if (accum) d.C[idx] += acc[i][j][r];
        else       d.C[idx]  = acc[i][j][r];
    }
}

// ---------------------------------------------------------------------------
// Split-T flash attention (unchanged).
// ---------------------------------------------------------------------------
__global__ __launch_bounds__(256) void k_attnp(const float* __restrict__ x_,
                                               const float* __restrict__ gh,
                                               float* __restrict__ ctxp,
                                               float2* __restrict__ msb) {
    int blk = blockIdx.x;
    int b = blk & (BB - 1), ch = blk >> 8;
    int tid = threadIdx.x, w = tid >> 6, lane = tid & 63;
    __shared__ float wm[4], ws[4];
    __shared__ float part[4][GG];

    const float* xb = x_ + (size_t)b * GG + lane * 8;
    float4 xa = *(const float4*)xb;
    float4 xc = *(const float4*)(xb + 4);

    float m = -INFINITY, s = 0.f;
    float acc[8] = {};
    int t0 = ch * 32 + w * 8;
#pragma unroll
    for (int it = 0; it < 8; ++it) {
        int t = t0 + it;
        const float* row = gh + ((size_t)t * BB + b) * GG + lane * 8;
        float4 v1 = *(const float4*)row;
        float4 v2 = *(const float4*)(row + 4);
        float p = v1.x*xa.x + v1.y*xa.y + v1.z*xa.z + v1.w*xa.w
                + v2.x*xc.x + v2.y*xc.y + v2.z*xc.z + v2.w*xc.w;
#pragma unroll
        for (int off = 32; off; off >>= 1) p += __shfl_xor(p, off);
        float nm = fmaxf(m, p);
        float scale = expf(m - nm);
        float e = expf(p - nm);
        s = s * scale + e;
        acc[0] = acc[0]*scale + e*v1.x; acc[1] = acc[1]*scale + e*v1.y;
        acc[2] = acc[2]*scale + e*v1.z; acc[3] = acc[3]*scale + e*v1.w;
        acc[4] = acc[4]*scale + e*v2.x; acc[5] = acc[5]*scale + e*v2.y;
        acc[6] = acc[6]*scale + e*v2.z; acc[7] = acc[7]*scale + e*v2.w;
        m = nm;
    }
    if (lane == 0) { wm[w] = m; ws[w] = s; }
    *(float4*)&part[w][lane * 8]     = make_float4(acc[0], acc[1], acc[2], acc[3]);
    *(float4*)&part[w][lane * 8 + 4] = make_float4(acc[4], acc[5], acc[6], acc[7]);
    __syncthreads();

    float M = fmaxf(fmaxf(wm[0], wm[1]), fmaxf(wm[2], wm[3]));
    float f0 = expf(wm[0] - M), f1 = expf(wm[1] - M);
    float f2 = expf(wm[2] - M), f3 = expf(wm[3] - M);
    if (tid == 0) {
        float S = ws[0]*f0 + ws[1]*f1 + ws[2]*f2 + ws[3]*f3;
        msb[blk] = make_float2(M, S);
    }
    for (int j = tid; j < GG; j += 256) {
        float r = part[0][j]*f0 + part[1][j]*f1 + part[2][j]*f2 + part[3][j]*f3;
        ctxp[(size_t)blk * GG + j] = r;
    }
}

// merge 8 chunk-partials per b -> ctx_bf
__global__ __launch_bounds__(256) void k_attnm(const float* __restrict__ ctxp,
                                               const float2* __restrict__ msb,
                                               short* __restrict__ ctx_bf) {
    int b = blockIdx.x, tid = threadIdx.x;
    float mv[8], sv[8];
    float M = -INFINITY;
#pragma unroll
    for (int c = 0; c < 8; ++c) {
        float2 t = msb[c * BB + b];
        mv[c] = t.x; sv[c] = t.y;
        M = fmaxf(M, t.x);
    }
    float S = 0.f;
    float f[8];
#pragma unroll
    for (int c = 0; c < 8; ++c) { f[c] = expf(mv[c] - M); S += sv[c] * f[c]; }
    float inv = 1.0f / S;
#pragma unroll
    for (int c = 0; c < 8; ++c) f[c] *= inv;
    for (int j = tid; j < GG; j += 256) {
        float r = 0.f;
#pragma unroll
        for (int c = 0; c < 8; ++c) r += ctxp[(size_t)(c * BB + b) * GG + j] * f[c];
        ctx_bf[(size_t)b * GG + j] = f2bf(r);
    }
}

// ---------------------------------------------------------------------------
// Fused GRU pair: [0, B*G) -> global GRU; [B*G, B*G+B*S) -> parties GRU
// ---------------------------------------------------------------------------
__global__ __launch_bounds__(256) void k_gru2(
        const float* __restrict__ gi_g, const float* __restrict__ gh_g,
        const float* __restrict__ bg_ih, const float* __restrict__ bg_hh,
        const float* __restrict__ hg, float* __restrict__ global_out,
        const float* __restrict__ gi_p, const float* __restrict__ gh_p,
        const float* __restrict__ bp_ih, const float* __restrict__ bp_hh,
        const float* __restrict__ sel0, const int* __restrict__ spk,
        short* __restrict__ par_bf, float* __restrict__ speaker_out) {
    int idx = blockIdx.x * 256 + threadIdx.x;
    if (idx < BB * GG) {
        int b = idx / GG, j = idx - b * GG;
        const float* gib = gi_g + (size_t)b * 3 * GG;
        const float* ghb = gh_g + (size_t)b * 3 * GG;
        float r = sigmoidf_(gib[j] + bg_ih[j] + ghb[j] + bg_hh[j]);
        float z = sigmoidf_(gib[GG + j] + bg_ih[GG + j] + ghb[GG + j] + bg_hh[GG + j]);
        float n = tanhf(gib[2*GG + j] + bg_ih[2*GG + j] + r * (ghb[2*GG + j] + bg_hh[2*GG + j]));
        global_out[idx] = (1.0f - z) * n + z * hg[idx];
    } else {
        idx -= BB * GG;
        int b = idx / SS, j = idx - b * SS;
        const float* gib = gi_p + (size_t)b * 3 * SS;
        const float* ghb = gh_p + (size_t)b * 3 * SS;
        float r = sigmoidf_(gib[j] + bp_ih[j] + ghb[j] + bp_hh[j]);
        float z = sigmoidf_(gib[SS + j] + bp_ih[SS + j] + ghb[SS + j] + bp_hh[SS + j]);
        float n = tanhf(gib[2*SS + j] + bp_ih[2*SS + j] + r * (ghb[2*SS + j] + bp_hh[2*SS + j]));
        float o = (1.0f - z) * n + z * sel0[idx];
        par_bf[idx] = f2bf(o);
        speaker_out[((size_t)b * PP + spk[b]) * SS + j] = o;
    }
}

// emotion GRU
__global__ __launch_bounds__(256) void k_gru(const float* __restrict__ gi, const float* __restrict__ gh,
                                             const float* __restrict__ bih, const float* __restrict__ bhh,
                                             const float* __restrict__ h,
                                             float* __restrict__ out, int H) {
    int idx = blockIdx.x * 256 + threadIdx.x;
    int b = idx / H, j = idx - b * H;
    const float* gib = gi + (size_t)b * 3 * H;
    const float* ghb = gh + (size_t)b * 3 * H;
    float r = sigmoidf_(gib[j] + bih[j] + ghb[j] + bhh[j]);
    float z = sigmoidf_(gib[H + j] + bih[H + j] + ghb[H + j] + bhh[H + j]);
    float n = tanhf(gib[2 * H + j] + bih[2 * H + j] + r * (ghb[2 * H + j] + bhh[2 * H + j]));
    out[idx] = (1.0f - z) * n + z * h[idx];
}

// ---------------------------------------------------------------------------
extern "C" void kernel_launch(void* const* d_in, const int* in_sizes, int n_in,
                              void* d_out, int out_size, void* d_ws, size_t ws_size,
                              hipStream_t stream) {
    const float* feature_ = (const float*)d_in[0];
    const float* mask     = (const float*)d_in[1];
    const float* ghist    = (const float*)d_in[2];
    const float* speaker0 = (const float*)d_in[3];
    const float* emotion0 = (const float*)d_in[4];
    const float* Wg_ih    = (const float*)d_in[5];
    const float* Wg_hh    = (const float*)d_in[6];
    const float* bg_ih    = (const float*)d_in[7];
    const float* bg_hh    = (const float*)d_in[8];
    const float* Wp_ih    = (const float*)d_in[9];
    const float* Wp_hh    = (const float*)d_in[10];
    const float* bp_ih    = (const float*)d_in[11];
    const float* bp_hh    = (const float*)d_in[12];
    const float* We_ih    = (const float*)d_in[13];
    const float* We_hh    = (const float*)d_in[14];
    const float* be_ih    = (const float*)d_in[15];
    const float* be_hh    = (const float*)d_in[16];
    const float* attn_W   = (const float*)d_in[17];

    float* out = (float*)d_out;
    float* emotion_out = out;
    float* global_out  = out + (size_t)BB * EE;
    float* speaker_out = global_out + (size_t)BB * GG;

    char* cur = (char*)d_ws;
    short* Wbf     = (short*)cur; cur += (size_t)WTOT * 2;
    short* awhi    = (short*)cur; cur += (size_t)GG * FF * 2;
    short* awlo    = (short*)cur; cur += (size_t)GG * FF * 2;
    short* xg      = (short*)cur; cur += (size_t)BB * 1536 * 2;
    short* fhi     = (short*)cur; cur += (size_t)BB * FF * 2;
    short* flo     = (short*)cur; cur += (size_t)BB * FF * 2;
    short* hg_bf   = (short*)cur; cur += (size_t)BB * GG * 2;
    short* emo_bf  = (short*)cur; cur += (size_t)BB * EE * 2;
    short* sel0_bf = (short*)cur; cur += (size_t)BB * SS * 2;
    short* ctx_bf  = (short*)cur; cur += (size_t)BB * GG * 2;
    short* par_bf  = (short*)cur; cur += (size_t)BB * SS * 2;

    float* sel0    = (float*)cur; cur += (size_t)BB * SS * 4;
    float* x_      = (float*)cur; cur += (size_t)BB * GG * 4;
    float* ctxp    = (float*)cur; cur += (size_t)2048 * GG * 4;
    float2* msb    = (float2*)cur; cur += (size_t)2048 * 8;
    float* gi_g    = (float*)cur; cur += (size_t)BB * 3 * GG * 4;
    float* gh_g    = (float*)cur; cur += (size_t)BB * 3 * GG * 4;
    float* gi_p    = (float*)cur; cur += (size_t)BB * 3 * SS * 4;
    float* gh_p    = (float*)cur; cur += (size_t)BB * 3 * SS * 4;
    float* gi_e    = (float*)cur; cur += (size_t)BB * 3 * EE * 4;
    float* gh_e    = (float*)cur; cur += (size_t)BB * 3 * EE * 4;
    int*   spk     = (int*)cur;   cur += 256 * 4;

    const float* h_g = ghist + (size_t)(TT - 1) * BB * GG;

    short* Wg_ih_bf = Wbf + OWG_IH;
    short* Wg_hh_bf = Wbf + OWG_HH;
    short* Wp_ih_bf = Wbf + OWP_IH;
    short* Wp_hh_bf = Wbf + OWP_HH;
    short* We_ih_bf = Wbf + OWE_IH;
    short* We_hh_bf = Wbf + OWE_HH;

    // 1) conversions + gather + speaker copy
    k_mega<<<MBE, 256, 0, stream>>>(Wg_ih, Wg_hh, Wp_ih, Wp_hh, We_ih, We_hh,
                                    attn_W, feature_, h_g, emotion0, mask, speaker0,
                                    Wbf, awhi, awlo, xg, fhi, flo, hg_bf, emo_bf,
                                    sel0_bf, sel0, spk, speaker_out);

    // 2) batchA: x_(split) + all attention-independent GEMMs
    GBatch gbA;
    gbA.d[0] = { fhi, flo, awhi, awlo, x_, FF, FF, FF, FF, 0, GG, FF, 8, 1 };
    gbA.d[1] = { xg, xg, Wg_ih_bf, nullptr, gi_g, 1536, 1536, 1536, 1536, 0, 3*GG, 1536, 24, 0 };
    gbA.d[2] = { hg_bf, hg_bf, Wg_hh_bf, nullptr, gh_g, GG, GG, GG, GG, 0, 3*GG, GG, 24, 0 };
    gbA.d[3] = { sel0_bf, sel0_bf, Wp_hh_bf, nullptr, gh_p, SS, SS, SS, SS, 0, 3*SS, SS, 24, 0 };
    gbA.d[4] = { emo_bf, emo_bf, We_hh_bf, nullptr, gh_e, EE, EE, EE, EE, 0, 3*EE, EE, 12, 0 };
    gbA.d[5] = { xg, xg, Wp_ih_bf, nullptr, gi_p, 1536, 1536, 1536, 1536, 0, 3*SS, FF, 24, 0 };
    gbA.start[0] = 0;   gbA.start[1] = 32;  gbA.start[2] = 128; gbA.start[3] = 224;
    gbA.start[4] = 320; gbA.start[5] = 368; gbA.start[6] = 464;
    gbA.ng = 6;
    k_bgemm<<<464, 256, 0, stream>>>(gbA);

    // 3) flash attention partials (single history read)
    k_attnp<<<2048, 256, 0, stream>>>(x_, ghist, ctxp, msb);

    // 4) merge partials -> ctx_bf
    k_attnm<<<BB, 256, 0, stream>>>(ctxp, msb, ctx_bf);

    // 5) gi_p += ctx @ Wp_ih[:, F:]^T (accumulate)
    GBatch gbB;
    gbB.d[0] = { ctx_bf, ctx_bf, Wp_ih_bf, nullptr, gi_p, GG, GG, GG, 1536, FF, 3*SS, GG, 24, 2 };
    gbB.start[0] = 0; gbB.start[1] = 96; gbB.ng = 1;
    k_bgemm<<<96, 256, 0, stream>>>(gbB);

    // 6) global GRU + parties GRU (+ scatter)
    k_gru2<<<(BB * GG + BB * SS) / 256, 256, 0, stream>>>(
        gi_g, gh_g, bg_ih, bg_hh, h_g, global_out,
        gi_p, gh_p, bp_ih, bp_hh, sel0, spk, par_bf, speaker_out);

    // 7) gi_e = parties @ We_ih^T
    GBatch gbC;
    gbC.d[0] = { par_bf, par_bf, We_ih_bf, nullptr, gi_e, SS, SS, SS, SS, 0, 3*EE, SS, 12, 0 };
    gbC.start[0] = 0; gbC.start[1] = 48; gbC.ng = 1;
    k_bgemm<<<48, 256, 0, stream>>>(gbC);

    // 8) emotion GRU
    k_gru<<<(BB * EE) / 256, 256, 0, stream>>>(gi_e, gh_e, be_ih, be_hh, emotion0, emotion_out, EE);
}